// Round 1
// 1315.260 us; speedup vs baseline: 1.1410x; 1.1410x over previous
//
#include <hip/hip_runtime.h>
#include <hip/hip_bf16.h>

#define NN 100000
#define EE 3200000
#define HD 64
#define NF 512
#define NC 256
#define NBLK 98   // ceil(100000/1024)

// ---- bucketed CSR-build parameters ----
#define BSH 8                 // 256 nodes per bucket
#define NB 391                // ceil(NN/256)
#define EB 8192               // edges per partition block
#define NEB 391               // ceil(EE/EB)

// ---------------- degree count ----------------

__global__ __launch_bounds__(256) void count_deg(const int* __restrict__ dst, int* __restrict__ cnt) {
    int e = blockIdx.x * 256 + threadIdx.x;
    if (e < EE) atomicAdd(&cnt[dst[e]], 1);
}

// ---------------- rowptr scan ----------------

__global__ __launch_bounds__(256) void scan_blocksum(const int* __restrict__ cnt, int* __restrict__ bsum) {
    __shared__ int s[256];
    int t = threadIdx.x, b = blockIdx.x;
    int base = b * 1024 + t * 4;
    int v = 0;
#pragma unroll
    for (int i = 0; i < 4; ++i) {
        int idx = base + i;
        if (idx < NN) v += cnt[idx];
    }
    s[t] = v; __syncthreads();
    for (int d = 128; d > 0; d >>= 1) {
        if (t < d) s[t] += s[t + d];
        __syncthreads();
    }
    if (t == 0) bsum[b] = s[0];
}

__global__ __launch_bounds__(128) void scan_offsets(int* __restrict__ bsum) {
    __shared__ int s[128];
    int t = threadIdx.x;
    int v = (t < NBLK) ? bsum[t] : 0;
    s[t] = v; __syncthreads();
    for (int d = 1; d < 128; d <<= 1) {
        int a = (t >= d) ? s[t - d] : 0;
        __syncthreads();
        s[t] += a;
        __syncthreads();
    }
    if (t < NBLK) bsum[t] = (t == 0) ? 0 : s[t - 1];  // exclusive
}

__global__ __launch_bounds__(256) void scan_write(const int* __restrict__ cnt, const int* __restrict__ bsum,
                                                  int* __restrict__ rowptr) {
    __shared__ int s[256];
    int t = threadIdx.x, b = blockIdx.x;
    int base = b * 1024 + t * 4;
    int v[4]; int tsum = 0;
#pragma unroll
    for (int i = 0; i < 4; ++i) {
        v[i] = (base + i < NN) ? cnt[base + i] : 0;
        tsum += v[i];
    }
    s[t] = tsum; __syncthreads();
    for (int d = 1; d < 256; d <<= 1) {
        int a = (t >= d) ? s[t - d] : 0;
        __syncthreads();
        s[t] += a;
        __syncthreads();
    }
    int off = bsum[b] + (s[t] - tsum);
#pragma unroll
    for (int i = 0; i < 4; ++i) {
        if (base + i < NN) rowptr[base + i] = off;
        off += v[i];
    }
    if (b == NBLK - 1 && t == 255) rowptr[NN] = bsum[b] + s[255];
}

__global__ __launch_bounds__(256) void init_inv(const int* __restrict__ cnt, float* __restrict__ inv) {
    int n = blockIdx.x * 256 + threadIdx.x;
    if (n < NN) {
        int c = cnt[n];
        inv[n] = 1.0f / (float)(c > 1 ? c : 1);
    }
}

// ---------------- bucketed edge partition ----------------
// Phase 1: per-(edge-block, bucket) histogram via LDS atomics.

__global__ __launch_bounds__(256) void part_count(const int* __restrict__ dst, int* __restrict__ hist) {
    __shared__ int hs[NB];
    int t = threadIdx.x, blk = blockIdx.x;
    for (int b = t; b < NB; b += 256) hs[b] = 0;
    __syncthreads();
    int base = blk * EB;
#pragma unroll
    for (int i = 0; i < EB / 256; ++i) {
        int e = base + t + 256 * i;
        if (e < EE) atomicAdd(&hs[dst[e] >> BSH], 1);
    }
    __syncthreads();
    for (int b = t; b < NB; b += 256) hist[blk * NB + b] = hs[b];
}

// Phase 2: per-bucket exclusive scan over edge-blocks, anchored at rowptr[bucket start].
// ebuf shares csr's index space: bucket b occupies [rowptr[b<<BSH], rowptr[min((b+1)<<BSH, NN)]).

__global__ __launch_bounds__(512) void part_scan(const int* __restrict__ hist, const int* __restrict__ rowptr,
                                                 int* __restrict__ bboff) {
    __shared__ int s[512];
    int b = blockIdx.x, t = threadIdx.x;
    int v = (t < NEB) ? hist[t * NB + b] : 0;
    s[t] = v; __syncthreads();
    for (int d = 1; d < 512; d <<= 1) {
        int a = (t >= d) ? s[t - d] : 0;
        __syncthreads();
        s[t] += a;
        __syncthreads();
    }
    if (t < NEB) bboff[t * NB + b] = rowptr[b << BSH] + s[t] - v;  // exclusive
}

// Phase 3: scatter packed (src | dstLocal<<17) into bucket-grouped runs. LDS rank counters,
// ~21-entry contiguous runs per (block,bucket) -> write-combining in this block's L2.

__global__ __launch_bounds__(256) void part_scatter(const int* __restrict__ src, const int* __restrict__ dst,
                                                    const int* __restrict__ bboff, unsigned int* __restrict__ ebuf) {
    __shared__ int off[NB];
    __shared__ int rank[NB];
    int t = threadIdx.x, blk = blockIdx.x;
    for (int b = t; b < NB; b += 256) { off[b] = bboff[blk * NB + b]; rank[b] = 0; }
    __syncthreads();
    int base = blk * EB;
#pragma unroll
    for (int i = 0; i < EB / 256; ++i) {
        int e = base + t + 256 * i;
        if (e < EE) {
            int d = dst[e];
            int s = src[e];
            int b = d >> BSH;
            int r = atomicAdd(&rank[b], 1);
            ebuf[off[b] + r] = (unsigned)s | ((unsigned)(d & 255) << 17);
        }
    }
}

// Phase 4: within-bucket sort to final csr. Cursors in LDS; csr writes confined to ~32 KB window.

__global__ __launch_bounds__(256) void bucket_fill(const unsigned int* __restrict__ ebuf,
                                                   const int* __restrict__ rowptr, int* __restrict__ csr) {
    __shared__ int cur[256];
    int t = threadIdx.x, b = blockIdx.x;
    int n0 = b << BSH;
    int nEnd = min(n0 + 256, NN);
    if (n0 + t < nEnd) cur[t] = rowptr[n0 + t];
    __syncthreads();
    int estart = rowptr[n0];
    int eend = rowptr[nEnd];
    for (int e = estart + t; e < eend; e += 256) {
        unsigned u = ebuf[e];
        int s = (int)(u & 0x1FFFFu);
        int dL = (int)(u >> 17);
        int p = atomicAdd(&cur[dL], 1);
        csr[p] = s;
    }
}

// ---------------- GEMM: h = x @ Win + b_in  [100000,512]x[512,64] ----------------

__global__ __launch_bounds__(256) void gemm_in(const float* __restrict__ x, const float* __restrict__ Win,
                                               const float* __restrict__ b_in, float* __restrict__ h) {
    __shared__ float xs[64 * 64];  // 16 KB
    int tid = threadIdx.x;
    int lane = tid & 63, wave = tid >> 6;
    int rowBase = blockIdx.x * 64;
    float bb = b_in[lane];
    float acc[16];
#pragma unroll
    for (int r = 0; r < 16; ++r) acc[r] = bb;

    for (int kt = 0; kt < NF; kt += 64) {
        __syncthreads();  // previous tile fully consumed
#pragma unroll
        for (int i = 0; i < 4; ++i) {
            int idx = tid + 256 * i;     // 0..1023
            int r = idx >> 4;            // tile row
            int c4 = idx & 15;           // float4 within row
            int grow = rowBase + r;
            if (grow >= NN) grow = NN - 1;
            float4 v = *(const float4*)(x + (size_t)grow * NF + kt + c4 * 4);
            *(float4*)(xs + r * 64 + c4 * 4) = v;
        }
        __syncthreads();
        const float* wsrc = Win + (size_t)kt * HD;
        for (int k = 0; k < 64; k += 4) {
            float w0 = wsrc[(k + 0) * HD + lane];
            float w1 = wsrc[(k + 1) * HD + lane];
            float w2 = wsrc[(k + 2) * HD + lane];
            float w3 = wsrc[(k + 3) * HD + lane];
#pragma unroll
            for (int r = 0; r < 16; ++r) {
                float4 xv = *(const float4*)(xs + (wave * 16 + r) * 64 + k);
                acc[r] = fmaf(xv.x, w0, acc[r]);
                acc[r] = fmaf(xv.y, w1, acc[r]);
                acc[r] = fmaf(xv.z, w2, acc[r]);
                acc[r] = fmaf(xv.w, w3, acc[r]);
            }
        }
    }
#pragma unroll
    for (int r = 0; r < 16; ++r) {
        int row = rowBase + wave * 16 + r;
        if (row < NN) h[(size_t)row * HD + lane] = acc[r];
    }
}

// ---------------- Aggregation: agg[n] = mean over in-edges of h[src] ----------------

__global__ __launch_bounds__(256) void aggregate(const float4* __restrict__ h4, const int* __restrict__ rowptr,
                                                 const int* __restrict__ csr, const float* __restrict__ inv,
                                                 float4* __restrict__ agg4) {
    int tid = threadIdx.x;
    int lane = tid & 63;
    int q = lane >> 4;
    int f = lane & 15;
    int node = blockIdx.x * 4 + (tid >> 6);
    int n = __builtin_amdgcn_readfirstlane(node);
    int start = rowptr[n];
    int end = rowptr[n + 1];

    float4 acc0 = make_float4(0.f, 0.f, 0.f, 0.f);
    float4 acc1 = make_float4(0.f, 0.f, 0.f, 0.f);
    int e = start;
    int end8 = start + ((end - start) & ~7);
    for (; e < end8; e += 8) {
        int s0 = csr[e + q];
        int s1 = csr[e + 4 + q];
        float4 v0 = h4[(size_t)s0 * 16 + f];
        float4 v1 = h4[(size_t)s1 * 16 + f];
        acc0.x += v0.x; acc0.y += v0.y; acc0.z += v0.z; acc0.w += v0.w;
        acc1.x += v1.x; acc1.y += v1.y; acc1.z += v1.z; acc1.w += v1.w;
    }
    if (e + q < end) {
        int s = csr[e + q];
        float4 v = h4[(size_t)s * 16 + f];
        acc0.x += v.x; acc0.y += v.y; acc0.z += v.z; acc0.w += v.w;
    }
    e += 4;
    if (e + q < end) {
        int s = csr[e + q];
        float4 v = h4[(size_t)s * 16 + f];
        acc1.x += v.x; acc1.y += v.y; acc1.z += v.z; acc1.w += v.w;
    }

    float4 a;
    a.x = acc0.x + acc1.x;
    a.y = acc0.y + acc1.y;
    a.z = acc0.z + acc1.z;
    a.w = acc0.w + acc1.w;
    a.x += __shfl_xor(a.x, 16); a.x += __shfl_xor(a.x, 32);
    a.y += __shfl_xor(a.y, 16); a.y += __shfl_xor(a.y, 32);
    a.z += __shfl_xor(a.z, 16); a.z += __shfl_xor(a.z, 32);
    a.w += __shfl_xor(a.w, 16); a.w += __shfl_xor(a.w, 32);

    if (q == 0) {
        float s = inv[n];
        float4 r;
        r.x = a.x * s; r.y = a.y * s; r.z = a.z * s; r.w = a.w * s;
        agg4[(size_t)n * 16 + f] = r;
    }
}

// ---------------- Layer: h = h + relu(agg@Wl + bl + h@Wr) ----------------

__global__ __launch_bounds__(256) void layer_conv(const float* __restrict__ agg, float* __restrict__ h,
                                                  const float* __restrict__ Wl, const float* __restrict__ Wr,
                                                  const float* __restrict__ bl) {
    __shared__ float as_[64 * 64];  // 16 KB
    __shared__ float hs[64 * 64];   // 16 KB
    int tid = threadIdx.x;
    int lane = tid & 63, wave = tid >> 6;
    int rowBase = blockIdx.x * 64;
    float bb = bl[lane];
    float acc[16];
#pragma unroll
    for (int r = 0; r < 16; ++r) acc[r] = bb;

#pragma unroll
    for (int i = 0; i < 4; ++i) {
        int idx = tid + 256 * i;
        int r = idx >> 4;
        int c4 = idx & 15;
        int grow = rowBase + r;
        if (grow >= NN) grow = NN - 1;
        *(float4*)(as_ + r * 64 + c4 * 4) = *(const float4*)(agg + (size_t)grow * HD + c4 * 4);
        *(float4*)(hs + r * 64 + c4 * 4) = *(const float4*)(h + (size_t)grow * HD + c4 * 4);
    }
    __syncthreads();

    for (int k = 0; k < 64; k += 4) {
        float wl0 = Wl[(k + 0) * HD + lane];
        float wl1 = Wl[(k + 1) * HD + lane];
        float wl2 = Wl[(k + 2) * HD + lane];
        float wl3 = Wl[(k + 3) * HD + lane];
        float wr0 = Wr[(k + 0) * HD + lane];
        float wr1 = Wr[(k + 1) * HD + lane];
        float wr2 = Wr[(k + 2) * HD + lane];
        float wr3 = Wr[(k + 3) * HD + lane];
#pragma unroll
        for (int r = 0; r < 16; ++r) {
            float4 av = *(const float4*)(as_ + (wave * 16 + r) * 64 + k);
            float4 hv = *(const float4*)(hs + (wave * 16 + r) * 64 + k);
            acc[r] = fmaf(av.x, wl0, acc[r]);
            acc[r] = fmaf(av.y, wl1, acc[r]);
            acc[r] = fmaf(av.z, wl2, acc[r]);
            acc[r] = fmaf(av.w, wl3, acc[r]);
            acc[r] = fmaf(hv.x, wr0, acc[r]);
            acc[r] = fmaf(hv.y, wr1, acc[r]);
            acc[r] = fmaf(hv.z, wr2, acc[r]);
            acc[r] = fmaf(hv.w, wr3, acc[r]);
        }
    }
#pragma unroll
    for (int r = 0; r < 16; ++r) {
        int row = rowBase + wave * 16 + r;
        if (row < NN) {
            float ho = hs[(wave * 16 + r) * 64 + lane];
            float c = acc[r];
            h[(size_t)row * HD + lane] = ho + (c > 0.f ? c : 0.f);
        }
    }
}

// ---------------- Output GEMM: out = h @ Wout + b_out ----------------

__global__ __launch_bounds__(256) void gemm_out_k(const float* __restrict__ h, const float* __restrict__ Wout,
                                                  const float* __restrict__ b_out, float* __restrict__ out) {
    __shared__ float hs[32 * 64];  // 8 KB
    int tid = threadIdx.x;
    int rowBase = blockIdx.x * 32;
#pragma unroll
    for (int i = 0; i < 2; ++i) {
        int idx = tid + 256 * i;  // 0..511
        int r = idx >> 4;
        int c4 = idx & 15;
        int grow = rowBase + r;
        if (grow >= NN) grow = NN - 1;
        *(float4*)(hs + r * 64 + c4 * 4) = *(const float4*)(h + (size_t)grow * HD + c4 * 4);
    }
    __syncthreads();

    int j = tid;  // output column
    float bb = b_out[j];
    float acc[32];
#pragma unroll
    for (int r = 0; r < 32; ++r) acc[r] = bb;

    for (int k = 0; k < 64; k += 4) {
        float w0 = Wout[(k + 0) * NC + j];
        float w1 = Wout[(k + 1) * NC + j];
        float w2 = Wout[(k + 2) * NC + j];
        float w3 = Wout[(k + 3) * NC + j];
#pragma unroll
        for (int r = 0; r < 32; ++r) {
            float4 hv = *(const float4*)(hs + r * 64 + k);
            acc[r] = fmaf(hv.x, w0, acc[r]);
            acc[r] = fmaf(hv.y, w1, acc[r]);
            acc[r] = fmaf(hv.z, w2, acc[r]);
            acc[r] = fmaf(hv.w, w3, acc[r]);
        }
    }
#pragma unroll
    for (int r = 0; r < 32; ++r) {
        int row = rowBase + r;
        if (row < NN) out[(size_t)row * NC + j] = acc[r];
    }
}

extern "C" void kernel_launch(void* const* d_in, const int* in_sizes, int n_in,
                              void* d_out, int out_size, void* d_ws, size_t ws_size,
                              hipStream_t stream) {
    const float* x    = (const float*)d_in[0];
    const int*   ei   = (const int*)d_in[1];   // [2, E]: src then dst
    const float* Win  = (const float*)d_in[2];
    const float* b_in = (const float*)d_in[3];
    const float* Wl   = (const float*)d_in[4]; // [4,64,64]
    const float* bl   = (const float*)d_in[5]; // [4,64]
    const float* Wr   = (const float*)d_in[6]; // [4,64,64]
    const float* Wout = (const float*)d_in[7];
    const float* b_out= (const float*)d_in[8];
    float* out = (float*)d_out;

    const int* src = ei;
    const int* dst = ei + EE;

    // workspace layout (16B-aligned chunks)
    char* ws = (char*)d_ws;
    float* h      = (float*)ws;                       // 6.4M floats
    float* agg    = h + (size_t)NN * HD;              // 6.4M floats
    int*   cnt    = (int*)(agg + (size_t)NN * HD);    // 100000
    int*   rowptr = cnt + NN;                         // 100001 (pad to 100004)
    int*   csr    = rowptr + 100004;                  // 3.2M
    float* inv    = (float*)(csr + EE);               // 100000
    int*   bsum   = (int*)(inv + NN);                 // 128

    // CSR-build scratch overlays on agg (dead until first aggregate):
    unsigned int* ebuf = (unsigned int*)agg;          // EE u32 (12.8 MB)
    int* hist  = (int*)agg + EE;                      // NEB*NB (611 KB)
    int* bboff = hist + NEB * NB;                     // NEB*NB (611 KB)

    hipMemsetAsync(cnt, 0, NN * sizeof(int), stream);

    count_deg<<<EE / 256, 256, 0, stream>>>(dst, cnt);
    scan_blocksum<<<NBLK, 256, 0, stream>>>(cnt, bsum);
    scan_offsets<<<1, 128, 0, stream>>>(bsum);
    scan_write<<<NBLK, 256, 0, stream>>>(cnt, bsum, rowptr);
    init_inv<<<(NN + 255) / 256, 256, 0, stream>>>(cnt, inv);

    part_count<<<NEB, 256, 0, stream>>>(dst, hist);
    part_scan<<<NB, 512, 0, stream>>>(hist, rowptr, bboff);
    part_scatter<<<NEB, 256, 0, stream>>>(src, dst, bboff, ebuf);
    bucket_fill<<<NB, 256, 0, stream>>>(ebuf, rowptr, csr);

    gemm_in<<<(NN + 63) / 64, 256, 0, stream>>>(x, Win, b_in, h);

    for (int i = 0; i < 4; ++i) {
        aggregate<<<NN / 4, 256, 0, stream>>>((const float4*)h, rowptr, csr, inv, (float4*)agg);
        layer_conv<<<(NN + 63) / 64, 256, 0, stream>>>(agg, h, Wl + (size_t)i * HD * HD,
                                                       Wr + (size_t)i * HD * HD, bl + (size_t)i * HD);
    }

    gemm_out_k<<<(NN + 31) / 32, 256, 0, stream>>>(h, Wout, b_out, out);
}

// Round 2
// 1190.687 us; speedup vs baseline: 1.2604x; 1.1046x over previous
//
#include <hip/hip_runtime.h>
#include <hip/hip_bf16.h>

#define NN 100000
#define EE 3200000
#define HD 64
#define NF 512
#define NC 256
#define NBLK 98   // ceil(100000/1024)

// ---- bucketed CSR-build parameters ----
#define BSH 8                 // 256 nodes per bucket
#define NB 391                // ceil(NN/256)
#define EB 8192               // edges per partition block
#define NEB 391               // ceil(EE/EB)

// ---------------- degree count ----------------

__global__ __launch_bounds__(256) void count_deg(const int* __restrict__ dst, int* __restrict__ cnt) {
    int e = blockIdx.x * 256 + threadIdx.x;
    if (e < EE) atomicAdd(&cnt[dst[e]], 1);
}

// ---------------- rowptr scan ----------------

__global__ __launch_bounds__(256) void scan_blocksum(const int* __restrict__ cnt, int* __restrict__ bsum) {
    __shared__ int s[256];
    int t = threadIdx.x, b = blockIdx.x;
    int base = b * 1024 + t * 4;
    int v = 0;
#pragma unroll
    for (int i = 0; i < 4; ++i) {
        int idx = base + i;
        if (idx < NN) v += cnt[idx];
    }
    s[t] = v; __syncthreads();
    for (int d = 128; d > 0; d >>= 1) {
        if (t < d) s[t] += s[t + d];
        __syncthreads();
    }
    if (t == 0) bsum[b] = s[0];
}

__global__ __launch_bounds__(128) void scan_offsets(int* __restrict__ bsum) {
    __shared__ int s[128];
    int t = threadIdx.x;
    int v = (t < NBLK) ? bsum[t] : 0;
    s[t] = v; __syncthreads();
    for (int d = 1; d < 128; d <<= 1) {
        int a = (t >= d) ? s[t - d] : 0;
        __syncthreads();
        s[t] += a;
        __syncthreads();
    }
    if (t < NBLK) bsum[t] = (t == 0) ? 0 : s[t - 1];  // exclusive
}

__global__ __launch_bounds__(256) void scan_write(const int* __restrict__ cnt, const int* __restrict__ bsum,
                                                  int* __restrict__ rowptr) {
    __shared__ int s[256];
    int t = threadIdx.x, b = blockIdx.x;
    int base = b * 1024 + t * 4;
    int v[4]; int tsum = 0;
#pragma unroll
    for (int i = 0; i < 4; ++i) {
        v[i] = (base + i < NN) ? cnt[base + i] : 0;
        tsum += v[i];
    }
    s[t] = tsum; __syncthreads();
    for (int d = 1; d < 256; d <<= 1) {
        int a = (t >= d) ? s[t - d] : 0;
        __syncthreads();
        s[t] += a;
        __syncthreads();
    }
    int off = bsum[b] + (s[t] - tsum);
#pragma unroll
    for (int i = 0; i < 4; ++i) {
        if (base + i < NN) rowptr[base + i] = off;
        off += v[i];
    }
    if (b == NBLK - 1 && t == 255) rowptr[NN] = bsum[b] + s[255];
}

__global__ __launch_bounds__(256) void init_inv(const int* __restrict__ cnt, float* __restrict__ inv) {
    int n = blockIdx.x * 256 + threadIdx.x;
    if (n < NN) {
        int c = cnt[n];
        inv[n] = 1.0f / (float)(c > 1 ? c : 1);
    }
}

// ---------------- bucketed edge partition ----------------

__global__ __launch_bounds__(256) void part_count(const int* __restrict__ dst, int* __restrict__ hist) {
    __shared__ int hs[NB];
    int t = threadIdx.x, blk = blockIdx.x;
    for (int b = t; b < NB; b += 256) hs[b] = 0;
    __syncthreads();
    int base = blk * EB;
#pragma unroll
    for (int i = 0; i < EB / 256; ++i) {
        int e = base + t + 256 * i;
        if (e < EE) atomicAdd(&hs[dst[e] >> BSH], 1);
    }
    __syncthreads();
    for (int b = t; b < NB; b += 256) hist[blk * NB + b] = hs[b];
}

__global__ __launch_bounds__(512) void part_scan(const int* __restrict__ hist, const int* __restrict__ rowptr,
                                                 int* __restrict__ bboff) {
    __shared__ int s[512];
    int b = blockIdx.x, t = threadIdx.x;
    int v = (t < NEB) ? hist[t * NB + b] : 0;
    s[t] = v; __syncthreads();
    for (int d = 1; d < 512; d <<= 1) {
        int a = (t >= d) ? s[t - d] : 0;
        __syncthreads();
        s[t] += a;
        __syncthreads();
    }
    if (t < NEB) bboff[t * NB + b] = rowptr[b << BSH] + s[t] - v;  // exclusive
}

__global__ __launch_bounds__(256) void part_scatter(const int* __restrict__ src, const int* __restrict__ dst,
                                                    const int* __restrict__ bboff, unsigned int* __restrict__ ebuf) {
    __shared__ int off[NB];
    __shared__ int rank[NB];
    int t = threadIdx.x, blk = blockIdx.x;
    for (int b = t; b < NB; b += 256) { off[b] = bboff[blk * NB + b]; rank[b] = 0; }
    __syncthreads();
    int base = blk * EB;
#pragma unroll
    for (int i = 0; i < EB / 256; ++i) {
        int e = base + t + 256 * i;
        if (e < EE) {
            int d = dst[e];
            int s = src[e];
            int b = d >> BSH;
            int r = atomicAdd(&rank[b], 1);
            ebuf[off[b] + r] = (unsigned)s | ((unsigned)(d & 255) << 17);
        }
    }
}

__global__ __launch_bounds__(256) void bucket_fill(const unsigned int* __restrict__ ebuf,
                                                   const int* __restrict__ rowptr, int* __restrict__ csr) {
    __shared__ int cur[256];
    int t = threadIdx.x, b = blockIdx.x;
    int n0 = b << BSH;
    int nEnd = min(n0 + 256, NN);
    if (n0 + t < nEnd) cur[t] = rowptr[n0 + t];
    __syncthreads();
    int estart = rowptr[n0];
    int eend = rowptr[nEnd];
    for (int e = estart + t; e < eend; e += 256) {
        unsigned u = ebuf[e];
        int s = (int)(u & 0x1FFFFu);
        int dL = (int)(u >> 17);
        int p = atomicAdd(&cur[dL], 1);
        csr[p] = s;
    }
}

// ---------------- GEMM: h = x @ Win + b_in  [100000,512]x[512,64] ----------------
// 128 rows x 64 cols per block; thread computes 8 rows x 4 cols (acc[8][4]).
// x tile + W tile staged in LDS (48 KB -> 3 blocks/CU). XOR swizzle on x tile
// so the 4 distinct-row broadcast reads per wave hit different bank groups.

__global__ __launch_bounds__(256) void gemm_in(const float* __restrict__ x, const float* __restrict__ Win,
                                               const float* __restrict__ b_in, float* __restrict__ h) {
    __shared__ float xs[128 * 64];  // 32 KB
    __shared__ float ws[64 * 64];   // 16 KB
    int tid = threadIdx.x;
    int cg = tid & 15;          // col quad: cols 4*cg..4*cg+3
    int rg = tid >> 4;          // row group: rows 8*rg..8*rg+7
    int rowBase = blockIdx.x * 128;
    float4 bb = *(const float4*)(b_in + cg * 4);
    float acc[8][4];
#pragma unroll
    for (int r = 0; r < 8; ++r) {
        acc[r][0] = bb.x; acc[r][1] = bb.y; acc[r][2] = bb.z; acc[r][3] = bb.w;
    }

    for (int kt = 0; kt < NF; kt += 64) {
        __syncthreads();  // previous tile consumed
#pragma unroll
        for (int i = 0; i < 8; ++i) {
            int idx = tid + 256 * i;     // 0..2047
            int r = idx >> 4;            // tile row 0..127
            int c4 = idx & 15;           // float4 within row
            int grow = rowBase + r;
            if (grow >= NN) grow = NN - 1;
            int c4s = c4 ^ ((r >> 3) & 3);
            *(float4*)(xs + r * 64 + c4s * 4) = *(const float4*)(x + (size_t)grow * NF + kt + c4 * 4);
        }
#pragma unroll
        for (int i = 0; i < 4; ++i) {
            int idx = tid + 256 * i;     // 0..1023
            int r = idx >> 4;            // k row 0..63
            int c4 = idx & 15;
            *(float4*)(ws + r * 64 + c4 * 4) = *(const float4*)(Win + (size_t)(kt + r) * HD + c4 * 4);
        }
        __syncthreads();
#pragma unroll 2
        for (int k = 0; k < 64; k += 4) {
            int kq = k >> 2;
            float4 w0 = *(const float4*)(ws + (k + 0) * 64 + cg * 4);
            float4 w1 = *(const float4*)(ws + (k + 1) * 64 + cg * 4);
            float4 w2 = *(const float4*)(ws + (k + 2) * 64 + cg * 4);
            float4 w3 = *(const float4*)(ws + (k + 3) * 64 + cg * 4);
#pragma unroll
            for (int r = 0; r < 8; ++r) {
                int row = rg * 8 + r;
                int c4s = kq ^ ((row >> 3) & 3);
                float4 xv = *(const float4*)(xs + row * 64 + c4s * 4);
                acc[r][0] = fmaf(xv.x, w0.x, acc[r][0]);
                acc[r][1] = fmaf(xv.x, w0.y, acc[r][1]);
                acc[r][2] = fmaf(xv.x, w0.z, acc[r][2]);
                acc[r][3] = fmaf(xv.x, w0.w, acc[r][3]);
                acc[r][0] = fmaf(xv.y, w1.x, acc[r][0]);
                acc[r][1] = fmaf(xv.y, w1.y, acc[r][1]);
                acc[r][2] = fmaf(xv.y, w1.z, acc[r][2]);
                acc[r][3] = fmaf(xv.y, w1.w, acc[r][3]);
                acc[r][0] = fmaf(xv.z, w2.x, acc[r][0]);
                acc[r][1] = fmaf(xv.z, w2.y, acc[r][1]);
                acc[r][2] = fmaf(xv.z, w2.z, acc[r][2]);
                acc[r][3] = fmaf(xv.z, w2.w, acc[r][3]);
                acc[r][0] = fmaf(xv.w, w3.x, acc[r][0]);
                acc[r][1] = fmaf(xv.w, w3.y, acc[r][1]);
                acc[r][2] = fmaf(xv.w, w3.z, acc[r][2]);
                acc[r][3] = fmaf(xv.w, w3.w, acc[r][3]);
            }
        }
    }
#pragma unroll
    for (int r = 0; r < 8; ++r) {
        int row = rowBase + rg * 8 + r;
        if (row < NN) {
            float4 o;
            o.x = acc[r][0]; o.y = acc[r][1]; o.z = acc[r][2]; o.w = acc[r][3];
            *(float4*)(h + (size_t)row * HD + cg * 4) = o;
        }
    }
}

// ---------------- Aggregation: agg[n] = mean over in-edges of h[src] ----------------

__global__ __launch_bounds__(256) void aggregate(const float4* __restrict__ h4, const int* __restrict__ rowptr,
                                                 const int* __restrict__ csr, const float* __restrict__ inv,
                                                 float4* __restrict__ agg4) {
    int tid = threadIdx.x;
    int lane = tid & 63;
    int q = lane >> 4;
    int f = lane & 15;
    int node = blockIdx.x * 4 + (tid >> 6);
    int n = __builtin_amdgcn_readfirstlane(node);
    int start = rowptr[n];
    int end = rowptr[n + 1];

    float4 acc0 = make_float4(0.f, 0.f, 0.f, 0.f);
    float4 acc1 = make_float4(0.f, 0.f, 0.f, 0.f);
    int e = start;
    int end8 = start + ((end - start) & ~7);
    for (; e < end8; e += 8) {
        int s0 = csr[e + q];
        int s1 = csr[e + 4 + q];
        float4 v0 = h4[(size_t)s0 * 16 + f];
        float4 v1 = h4[(size_t)s1 * 16 + f];
        acc0.x += v0.x; acc0.y += v0.y; acc0.z += v0.z; acc0.w += v0.w;
        acc1.x += v1.x; acc1.y += v1.y; acc1.z += v1.z; acc1.w += v1.w;
    }
    if (e + q < end) {
        int s = csr[e + q];
        float4 v = h4[(size_t)s * 16 + f];
        acc0.x += v.x; acc0.y += v.y; acc0.z += v.z; acc0.w += v.w;
    }
    e += 4;
    if (e + q < end) {
        int s = csr[e + q];
        float4 v = h4[(size_t)s * 16 + f];
        acc1.x += v.x; acc1.y += v.y; acc1.z += v.z; acc1.w += v.w;
    }

    float4 a;
    a.x = acc0.x + acc1.x;
    a.y = acc0.y + acc1.y;
    a.z = acc0.z + acc1.z;
    a.w = acc0.w + acc1.w;
    a.x += __shfl_xor(a.x, 16); a.x += __shfl_xor(a.x, 32);
    a.y += __shfl_xor(a.y, 16); a.y += __shfl_xor(a.y, 32);
    a.z += __shfl_xor(a.z, 16); a.z += __shfl_xor(a.z, 32);
    a.w += __shfl_xor(a.w, 16); a.w += __shfl_xor(a.w, 32);

    if (q == 0) {
        float s = inv[n];
        float4 r;
        r.x = a.x * s; r.y = a.y * s; r.z = a.z * s; r.w = a.w * s;
        agg4[(size_t)n * 16 + f] = r;
    }
}

// ---------------- Layer: h = h + relu(agg@Wl + bl + h@Wr) ----------------
// 64 rows x 64 cols per block; thread = 4 rows x 4 cols. Weights from global (L1/L2).
// XOR swizzle on both LDS tiles.

__global__ __launch_bounds__(256) void layer_conv(const float* __restrict__ agg, float* __restrict__ h,
                                                  const float* __restrict__ Wl, const float* __restrict__ Wr,
                                                  const float* __restrict__ bl) {
    __shared__ float as_[64 * 64];  // 16 KB
    __shared__ float hs[64 * 64];   // 16 KB
    int tid = threadIdx.x;
    int cg = tid & 15;      // cols 4*cg..4*cg+3
    int rg = tid >> 4;      // rows 4*rg..4*rg+3
    int rowBase = blockIdx.x * 64;
    float4 bb = *(const float4*)(bl + cg * 4);
    float acc[4][4];
#pragma unroll
    for (int r = 0; r < 4; ++r) {
        acc[r][0] = bb.x; acc[r][1] = bb.y; acc[r][2] = bb.z; acc[r][3] = bb.w;
    }

#pragma unroll
    for (int i = 0; i < 4; ++i) {
        int idx = tid + 256 * i;   // 0..1023
        int r = idx >> 4;          // row 0..63
        int c4 = idx & 15;
        int grow = rowBase + r;
        if (grow >= NN) grow = NN - 1;
        int c4s = c4 ^ ((r >> 2) & 3);
        *(float4*)(as_ + r * 64 + c4s * 4) = *(const float4*)(agg + (size_t)grow * HD + c4 * 4);
        *(float4*)(hs + r * 64 + c4s * 4) = *(const float4*)(h + (size_t)grow * HD + c4 * 4);
    }
    __syncthreads();

#pragma unroll 2
    for (int k = 0; k < 64; k += 4) {
        int kq = k >> 2;
        float4 l0 = *(const float4*)(Wl + (size_t)(k + 0) * HD + cg * 4);
        float4 l1 = *(const float4*)(Wl + (size_t)(k + 1) * HD + cg * 4);
        float4 l2 = *(const float4*)(Wl + (size_t)(k + 2) * HD + cg * 4);
        float4 l3 = *(const float4*)(Wl + (size_t)(k + 3) * HD + cg * 4);
        float4 r0 = *(const float4*)(Wr + (size_t)(k + 0) * HD + cg * 4);
        float4 r1 = *(const float4*)(Wr + (size_t)(k + 1) * HD + cg * 4);
        float4 r2 = *(const float4*)(Wr + (size_t)(k + 2) * HD + cg * 4);
        float4 r3 = *(const float4*)(Wr + (size_t)(k + 3) * HD + cg * 4);
#pragma unroll
        for (int r = 0; r < 4; ++r) {
            int row = rg * 4 + r;
            int c4s = kq ^ ((row >> 2) & 3);
            float4 av = *(const float4*)(as_ + row * 64 + c4s * 4);
            float4 hv = *(const float4*)(hs + row * 64 + c4s * 4);
            acc[r][0] = fmaf(av.x, l0.x, acc[r][0]);
            acc[r][1] = fmaf(av.x, l0.y, acc[r][1]);
            acc[r][2] = fmaf(av.x, l0.z, acc[r][2]);
            acc[r][3] = fmaf(av.x, l0.w, acc[r][3]);
            acc[r][0] = fmaf(av.y, l1.x, acc[r][0]);
            acc[r][1] = fmaf(av.y, l1.y, acc[r][1]);
            acc[r][2] = fmaf(av.y, l1.z, acc[r][2]);
            acc[r][3] = fmaf(av.y, l1.w, acc[r][3]);
            acc[r][0] = fmaf(av.z, l2.x, acc[r][0]);
            acc[r][1] = fmaf(av.z, l2.y, acc[r][1]);
            acc[r][2] = fmaf(av.z, l2.z, acc[r][2]);
            acc[r][3] = fmaf(av.z, l2.w, acc[r][3]);
            acc[r][0] = fmaf(av.w, l3.x, acc[r][0]);
            acc[r][1] = fmaf(av.w, l3.y, acc[r][1]);
            acc[r][2] = fmaf(av.w, l3.z, acc[r][2]);
            acc[r][3] = fmaf(av.w, l3.w, acc[r][3]);
            acc[r][0] = fmaf(hv.x, r0.x, acc[r][0]);
            acc[r][1] = fmaf(hv.x, r0.y, acc[r][1]);
            acc[r][2] = fmaf(hv.x, r0.z, acc[r][2]);
            acc[r][3] = fmaf(hv.x, r0.w, acc[r][3]);
            acc[r][0] = fmaf(hv.y, r1.x, acc[r][0]);
            acc[r][1] = fmaf(hv.y, r1.y, acc[r][1]);
            acc[r][2] = fmaf(hv.y, r1.z, acc[r][2]);
            acc[r][3] = fmaf(hv.y, r1.w, acc[r][3]);
            acc[r][0] = fmaf(hv.z, r2.x, acc[r][0]);
            acc[r][1] = fmaf(hv.z, r2.y, acc[r][1]);
            acc[r][2] = fmaf(hv.z, r2.z, acc[r][2]);
            acc[r][3] = fmaf(hv.z, r2.w, acc[r][3]);
            acc[r][0] = fmaf(hv.w, r3.x, acc[r][0]);
            acc[r][1] = fmaf(hv.w, r3.y, acc[r][1]);
            acc[r][2] = fmaf(hv.w, r3.z, acc[r][2]);
            acc[r][3] = fmaf(hv.w, r3.w, acc[r][3]);
        }
    }

#pragma unroll
    for (int r = 0; r < 4; ++r) {
        int row = rowBase + rg * 4 + r;
        if (row < NN) {
            int lrow = rg * 4 + r;
            int c4s = cg ^ ((lrow >> 2) & 3);
            float4 ho = *(const float4*)(hs + lrow * 64 + c4s * 4);
            float4 o;
            float c0 = acc[r][0], c1 = acc[r][1], c2 = acc[r][2], c3 = acc[r][3];
            o.x = ho.x + (c0 > 0.f ? c0 : 0.f);
            o.y = ho.y + (c1 > 0.f ? c1 : 0.f);
            o.z = ho.z + (c2 > 0.f ? c2 : 0.f);
            o.w = ho.w + (c3 > 0.f ? c3 : 0.f);
            *(float4*)(h + (size_t)row * HD + cg * 4) = o;
        }
    }
}

// ---------------- Output GEMM: out = h @ Wout + b_out  [100000,64]x[64,256] ----------------
// 32 rows x 256 cols per block; thread = 8 rows x 4 cols; rows are wave-uniform
// (rg = tid>>6) so all hs reads are free broadcasts; Wout loads coalesced.

__global__ __launch_bounds__(256) void gemm_out_k(const float* __restrict__ h, const float* __restrict__ Wout,
                                                  const float* __restrict__ b_out, float* __restrict__ out) {
    __shared__ float hs[32 * 64];  // 8 KB
    int tid = threadIdx.x;
    int cg = tid & 63;       // cols 4*cg..4*cg+3 (0..255)
    int rg = tid >> 6;       // rows 8*rg..8*rg+7 (wave-uniform)
    int rowBase = blockIdx.x * 32;
#pragma unroll
    for (int i = 0; i < 2; ++i) {
        int idx = tid + 256 * i;  // 0..511
        int r = idx >> 4;
        int c4 = idx & 15;
        int grow = rowBase + r;
        if (grow >= NN) grow = NN - 1;
        *(float4*)(hs + r * 64 + c4 * 4) = *(const float4*)(h + (size_t)grow * HD + c4 * 4);
    }
    __syncthreads();

    float4 bb = *(const float4*)(b_out + cg * 4);
    float acc[8][4];
#pragma unroll
    for (int r = 0; r < 8; ++r) {
        acc[r][0] = bb.x; acc[r][1] = bb.y; acc[r][2] = bb.z; acc[r][3] = bb.w;
    }

#pragma unroll 2
    for (int k = 0; k < 64; k += 4) {
        float4 w0 = *(const float4*)(Wout + (size_t)(k + 0) * NC + cg * 4);
        float4 w1 = *(const float4*)(Wout + (size_t)(k + 1) * NC + cg * 4);
        float4 w2 = *(const float4*)(Wout + (size_t)(k + 2) * NC + cg * 4);
        float4 w3 = *(const float4*)(Wout + (size_t)(k + 3) * NC + cg * 4);
#pragma unroll
        for (int r = 0; r < 8; ++r) {
            float4 hv = *(const float4*)(hs + (rg * 8 + r) * 64 + k);
            acc[r][0] = fmaf(hv.x, w0.x, acc[r][0]);
            acc[r][1] = fmaf(hv.x, w0.y, acc[r][1]);
            acc[r][2] = fmaf(hv.x, w0.z, acc[r][2]);
            acc[r][3] = fmaf(hv.x, w0.w, acc[r][3]);
            acc[r][0] = fmaf(hv.y, w1.x, acc[r][0]);
            acc[r][1] = fmaf(hv.y, w1.y, acc[r][1]);
            acc[r][2] = fmaf(hv.y, w1.z, acc[r][2]);
            acc[r][3] = fmaf(hv.y, w1.w, acc[r][3]);
            acc[r][0] = fmaf(hv.z, w2.x, acc[r][0]);
            acc[r][1] = fmaf(hv.z, w2.y, acc[r][1]);
            acc[r][2] = fmaf(hv.z, w2.z, acc[r][2]);
            acc[r][3] = fmaf(hv.z, w2.w, acc[r][3]);
            acc[r][0] = fmaf(hv.w, w3.x, acc[r][0]);
            acc[r][1] = fmaf(hv.w, w3.y, acc[r][1]);
            acc[r][2] = fmaf(hv.w, w3.z, acc[r][2]);
            acc[r][3] = fmaf(hv.w, w3.w, acc[r][3]);
        }
    }
#pragma unroll
    for (int r = 0; r < 8; ++r) {
        int row = rowBase + rg * 8 + r;
        if (row < NN) {
            float4 o;
            o.x = acc[r][0]; o.y = acc[r][1]; o.z = acc[r][2]; o.w = acc[r][3];
            *(float4*)(out + (size_t)row * NC + cg * 4) = o;
        }
    }
}

extern "C" void kernel_launch(void* const* d_in, const int* in_sizes, int n_in,
                              void* d_out, int out_size, void* d_ws, size_t ws_size,
                              hipStream_t stream) {
    const float* x    = (const float*)d_in[0];
    const int*   ei   = (const int*)d_in[1];   // [2, E]: src then dst
    const float* Win  = (const float*)d_in[2];
    const float* b_in = (const float*)d_in[3];
    const float* Wl   = (const float*)d_in[4]; // [4,64,64]
    const float* bl   = (const float*)d_in[5]; // [4,64]
    const float* Wr   = (const float*)d_in[6]; // [4,64,64]
    const float* Wout = (const float*)d_in[7];
    const float* b_out= (const float*)d_in[8];
    float* out = (float*)d_out;

    const int* src = ei;
    const int* dst = ei + EE;

    // workspace layout (16B-aligned chunks)
    char* ws = (char*)d_ws;
    float* h      = (float*)ws;                       // 6.4M floats
    float* agg    = h + (size_t)NN * HD;              // 6.4M floats
    int*   cnt    = (int*)(agg + (size_t)NN * HD);    // 100000
    int*   rowptr = cnt + NN;                         // 100001 (pad to 100004)
    int*   csr    = rowptr + 100004;                  // 3.2M
    float* inv    = (float*)(csr + EE);               // 100000
    int*   bsum   = (int*)(inv + NN);                 // 128

    // CSR-build scratch overlays on agg (dead until first aggregate):
    unsigned int* ebuf = (unsigned int*)agg;          // EE u32 (12.8 MB)
    int* hist  = (int*)agg + EE;                      // NEB*NB (611 KB)
    int* bboff = hist + NEB * NB;                     // NEB*NB (611 KB)

    hipMemsetAsync(cnt, 0, NN * sizeof(int), stream);

    count_deg<<<EE / 256, 256, 0, stream>>>(dst, cnt);
    scan_blocksum<<<NBLK, 256, 0, stream>>>(cnt, bsum);
    scan_offsets<<<1, 128, 0, stream>>>(bsum);
    scan_write<<<NBLK, 256, 0, stream>>>(cnt, bsum, rowptr);
    init_inv<<<(NN + 255) / 256, 256, 0, stream>>>(cnt, inv);

    part_count<<<NEB, 256, 0, stream>>>(dst, hist);
    part_scan<<<NB, 512, 0, stream>>>(hist, rowptr, bboff);
    part_scatter<<<NEB, 256, 0, stream>>>(src, dst, bboff, ebuf);
    bucket_fill<<<NB, 256, 0, stream>>>(ebuf, rowptr, csr);

    gemm_in<<<(NN + 127) / 128, 256, 0, stream>>>(x, Win, b_in, h);

    for (int i = 0; i < 4; ++i) {
        aggregate<<<NN / 4, 256, 0, stream>>>((const float4*)h, rowptr, csr, inv, (float4*)agg);
        layer_conv<<<(NN + 63) / 64, 256, 0, stream>>>(agg, h, Wl + (size_t)i * HD * HD,
                                                       Wr + (size_t)i * HD * HD, bl + (size_t)i * HD);
    }

    gemm_out_k<<<(NN + 31) / 32, 256, 0, stream>>>(h, Wout, b_out, out);
}

// Round 3
// 1093.988 us; speedup vs baseline: 1.3718x; 1.0884x over previous
//
#include <hip/hip_runtime.h>
#include <hip/hip_bf16.h>

#define NN 100000
#define EE 3200000
#define HD 64
#define NF 512
#define NC 256

// ---- bucketed CSR-build parameters ----
#define BSH 8                 // 256 nodes per bucket
#define NB 391                // ceil(NN/256)
#define EB 8192               // edges per partition block
#define NEB 391               // ceil(EE/EB)

// ---------------- bucketed edge partition ----------------
// Phase 1: per-(edge-block, bucket) histogram via LDS atomics.

__global__ __launch_bounds__(256) void part_count(const int* __restrict__ dst, int* __restrict__ hist) {
    __shared__ int hs[NB];
    int t = threadIdx.x, blk = blockIdx.x;
    for (int b = t; b < NB; b += 256) hs[b] = 0;
    __syncthreads();
    int base = blk * EB;
#pragma unroll
    for (int i = 0; i < EB / 256; ++i) {
        int e = base + t + 256 * i;
        if (e < EE) atomicAdd(&hs[dst[e] >> BSH], 1);
    }
    __syncthreads();
    for (int b = t; b < NB; b += 256) hist[blk * NB + b] = hs[b];
}

// Phase 1b: per-bucket totals + exclusive scan -> bucketptr[NB+1].

__global__ __launch_bounds__(512) void bucket_ptr(const int* __restrict__ hist, int* __restrict__ bucketptr) {
    __shared__ int s[512];
    int t = threadIdx.x;
    int v = 0;
    if (t < NB) {
        for (int blk = 0; blk < NEB; ++blk) v += hist[blk * NB + t];
    }
    s[t] = v; __syncthreads();
    for (int d = 1; d < 512; d <<= 1) {
        int a = (t >= d) ? s[t - d] : 0;
        __syncthreads();
        s[t] += a;
        __syncthreads();
    }
    if (t < NB) bucketptr[t] = s[t] - v;  // exclusive
    if (t == 0) bucketptr[NB] = EE;
}

// Phase 2: per-bucket exclusive scan over edge-blocks, anchored at bucketptr[b].

__global__ __launch_bounds__(512) void part_scan(const int* __restrict__ hist, const int* __restrict__ bucketptr,
                                                 int* __restrict__ bboff) {
    __shared__ int s[512];
    int b = blockIdx.x, t = threadIdx.x;
    int v = (t < NEB) ? hist[t * NB + b] : 0;
    s[t] = v; __syncthreads();
    for (int d = 1; d < 512; d <<= 1) {
        int a = (t >= d) ? s[t - d] : 0;
        __syncthreads();
        s[t] += a;
        __syncthreads();
    }
    if (t < NEB) bboff[t * NB + b] = bucketptr[b] + s[t] - v;  // exclusive
}

// Phase 3: scatter packed (src | dstLocal<<17) into bucket-grouped runs.

__global__ __launch_bounds__(256) void part_scatter(const int* __restrict__ src, const int* __restrict__ dst,
                                                    const int* __restrict__ bboff, unsigned int* __restrict__ ebuf) {
    __shared__ int off[NB];
    __shared__ int rank[NB];
    int t = threadIdx.x, blk = blockIdx.x;
    for (int b = t; b < NB; b += 256) { off[b] = bboff[blk * NB + b]; rank[b] = 0; }
    __syncthreads();
    int base = blk * EB;
#pragma unroll
    for (int i = 0; i < EB / 256; ++i) {
        int e = base + t + 256 * i;
        if (e < EE) {
            int d = dst[e];
            int s = src[e];
            int b = d >> BSH;
            int r = atomicAdd(&rank[b], 1);
            ebuf[off[b] + r] = (unsigned)s | ((unsigned)(d & 255) << 17);
        }
    }
}

// Phase 4: per-bucket node histogram + scan -> rowptr & inv, then scatter to csr.
// All atomics LDS-scope; csr writes confined to a ~32 KB window.

__global__ __launch_bounds__(256) void bucket_fill2(const unsigned int* __restrict__ ebuf,
                                                    const int* __restrict__ bucketptr,
                                                    int* __restrict__ rowptr, float* __restrict__ inv,
                                                    int* __restrict__ csr) {
    __shared__ int hcnt[256];
    __shared__ int scn[256];
    __shared__ int cur[256];
    int t = threadIdx.x, b = blockIdx.x;
    int n0 = b << BSH;
    hcnt[t] = 0;
    __syncthreads();
    int estart = bucketptr[b];
    int eend = bucketptr[b + 1];
    for (int e = estart + t; e < eend; e += 256) {
        atomicAdd(&hcnt[ebuf[e] >> 17], 1);
    }
    __syncthreads();
    int v = hcnt[t];
    scn[t] = v;
    __syncthreads();
    for (int d = 1; d < 256; d <<= 1) {
        int a = (t >= d) ? scn[t - d] : 0;
        __syncthreads();
        scn[t] += a;
        __syncthreads();
    }
    int off = estart + scn[t] - v;  // exclusive within bucket
    cur[t] = off;
    if (n0 + t < NN) {
        rowptr[n0 + t] = off;
        inv[n0 + t] = 1.0f / (float)(v > 1 ? v : 1);
    }
    if (b == NB - 1 && t == 0) rowptr[NN] = EE;
    __syncthreads();
    for (int e = estart + t; e < eend; e += 256) {
        unsigned u = ebuf[e];
        int dL = (int)(u >> 17);
        int p = atomicAdd(&cur[dL], 1);
        csr[p] = (int)(u & 0x1FFFFu);
    }
}

// ---------------- GEMM: h = x @ Win + b_in  [100000,512]x[512,64] ----------------
// 128 rows x 64 cols per block; thread computes 8 rows x 4 cols (acc[8][4]).

__global__ __launch_bounds__(256) void gemm_in(const float* __restrict__ x, const float* __restrict__ Win,
                                               const float* __restrict__ b_in, float* __restrict__ h) {
    __shared__ float xs[128 * 64];  // 32 KB
    __shared__ float ws[64 * 64];   // 16 KB
    int tid = threadIdx.x;
    int cg = tid & 15;          // col quad: cols 4*cg..4*cg+3
    int rg = tid >> 4;          // row group: rows 8*rg..8*rg+7
    int rowBase = blockIdx.x * 128;
    float4 bb = *(const float4*)(b_in + cg * 4);
    float acc[8][4];
#pragma unroll
    for (int r = 0; r < 8; ++r) {
        acc[r][0] = bb.x; acc[r][1] = bb.y; acc[r][2] = bb.z; acc[r][3] = bb.w;
    }

    for (int kt = 0; kt < NF; kt += 64) {
        __syncthreads();  // previous tile consumed
#pragma unroll
        for (int i = 0; i < 8; ++i) {
            int idx = tid + 256 * i;     // 0..2047
            int r = idx >> 4;            // tile row 0..127
            int c4 = idx & 15;           // float4 within row
            int grow = rowBase + r;
            if (grow >= NN) grow = NN - 1;
            int c4s = c4 ^ ((r >> 3) & 3);
            *(float4*)(xs + r * 64 + c4s * 4) = *(const float4*)(x + (size_t)grow * NF + kt + c4 * 4);
        }
#pragma unroll
        for (int i = 0; i < 4; ++i) {
            int idx = tid + 256 * i;     // 0..1023
            int r = idx >> 4;            // k row 0..63
            int c4 = idx & 15;
            *(float4*)(ws + r * 64 + c4 * 4) = *(const float4*)(Win + (size_t)(kt + r) * HD + c4 * 4);
        }
        __syncthreads();
#pragma unroll 2
        for (int k = 0; k < 64; k += 4) {
            int kq = k >> 2;
            float4 w0 = *(const float4*)(ws + (k + 0) * 64 + cg * 4);
            float4 w1 = *(const float4*)(ws + (k + 1) * 64 + cg * 4);
            float4 w2 = *(const float4*)(ws + (k + 2) * 64 + cg * 4);
            float4 w3 = *(const float4*)(ws + (k + 3) * 64 + cg * 4);
#pragma unroll
            for (int r = 0; r < 8; ++r) {
                int row = rg * 8 + r;
                int c4s = kq ^ ((row >> 3) & 3);
                float4 xv = *(const float4*)(xs + row * 64 + c4s * 4);
                acc[r][0] = fmaf(xv.x, w0.x, acc[r][0]);
                acc[r][1] = fmaf(xv.x, w0.y, acc[r][1]);
                acc[r][2] = fmaf(xv.x, w0.z, acc[r][2]);
                acc[r][3] = fmaf(xv.x, w0.w, acc[r][3]);
                acc[r][0] = fmaf(xv.y, w1.x, acc[r][0]);
                acc[r][1] = fmaf(xv.y, w1.y, acc[r][1]);
                acc[r][2] = fmaf(xv.y, w1.z, acc[r][2]);
                acc[r][3] = fmaf(xv.y, w1.w, acc[r][3]);
                acc[r][0] = fmaf(xv.z, w2.x, acc[r][0]);
                acc[r][1] = fmaf(xv.z, w2.y, acc[r][1]);
                acc[r][2] = fmaf(xv.z, w2.z, acc[r][2]);
                acc[r][3] = fmaf(xv.z, w2.w, acc[r][3]);
                acc[r][0] = fmaf(xv.w, w3.x, acc[r][0]);
                acc[r][1] = fmaf(xv.w, w3.y, acc[r][1]);
                acc[r][2] = fmaf(xv.w, w3.z, acc[r][2]);
                acc[r][3] = fmaf(xv.w, w3.w, acc[r][3]);
            }
        }
    }
#pragma unroll
    for (int r = 0; r < 8; ++r) {
        int row = rowBase + rg * 8 + r;
        if (row < NN) {
            float4 o;
            o.x = acc[r][0]; o.y = acc[r][1]; o.z = acc[r][2]; o.w = acc[r][3];
            *(float4*)(h + (size_t)row * HD + cg * 4) = o;
        }
    }
}

// ---------------- Aggregation: agg[n] = mean over in-edges of h[src] ----------------

__global__ __launch_bounds__(256) void aggregate(const float4* __restrict__ h4, const int* __restrict__ rowptr,
                                                 const int* __restrict__ csr, const float* __restrict__ inv,
                                                 float4* __restrict__ agg4) {
    int tid = threadIdx.x;
    int lane = tid & 63;
    int q = lane >> 4;
    int f = lane & 15;
    int node = blockIdx.x * 4 + (tid >> 6);
    int n = __builtin_amdgcn_readfirstlane(node);
    int start = rowptr[n];
    int end = rowptr[n + 1];

    float4 acc0 = make_float4(0.f, 0.f, 0.f, 0.f);
    float4 acc1 = make_float4(0.f, 0.f, 0.f, 0.f);
    int e = start;
    int end8 = start + ((end - start) & ~7);
    for (; e < end8; e += 8) {
        int s0 = csr[e + q];
        int s1 = csr[e + 4 + q];
        float4 v0 = h4[(size_t)s0 * 16 + f];
        float4 v1 = h4[(size_t)s1 * 16 + f];
        acc0.x += v0.x; acc0.y += v0.y; acc0.z += v0.z; acc0.w += v0.w;
        acc1.x += v1.x; acc1.y += v1.y; acc1.z += v1.z; acc1.w += v1.w;
    }
    if (e + q < end) {
        int s = csr[e + q];
        float4 v = h4[(size_t)s * 16 + f];
        acc0.x += v.x; acc0.y += v.y; acc0.z += v.z; acc0.w += v.w;
    }
    e += 4;
    if (e + q < end) {
        int s = csr[e + q];
        float4 v = h4[(size_t)s * 16 + f];
        acc1.x += v.x; acc1.y += v.y; acc1.z += v.z; acc1.w += v.w;
    }

    float4 a;
    a.x = acc0.x + acc1.x;
    a.y = acc0.y + acc1.y;
    a.z = acc0.z + acc1.z;
    a.w = acc0.w + acc1.w;
    a.x += __shfl_xor(a.x, 16); a.x += __shfl_xor(a.x, 32);
    a.y += __shfl_xor(a.y, 16); a.y += __shfl_xor(a.y, 32);
    a.z += __shfl_xor(a.z, 16); a.z += __shfl_xor(a.z, 32);
    a.w += __shfl_xor(a.w, 16); a.w += __shfl_xor(a.w, 32);

    if (q == 0) {
        float s = inv[n];
        float4 r;
        r.x = a.x * s; r.y = a.y * s; r.z = a.z * s; r.w = a.w * s;
        agg4[(size_t)n * 16 + f] = r;
    }
}

// ---------------- Layer: h = h + relu(agg@Wl + bl + h@Wr) ----------------

__global__ __launch_bounds__(256) void layer_conv(const float* __restrict__ agg, float* __restrict__ h,
                                                  const float* __restrict__ Wl, const float* __restrict__ Wr,
                                                  const float* __restrict__ bl) {
    __shared__ float as_[64 * 64];  // 16 KB
    __shared__ float hs[64 * 64];   // 16 KB
    int tid = threadIdx.x;
    int cg = tid & 15;      // cols 4*cg..4*cg+3
    int rg = tid >> 4;      // rows 4*rg..4*rg+3
    int rowBase = blockIdx.x * 64;
    float4 bb = *(const float4*)(bl + cg * 4);
    float acc[4][4];
#pragma unroll
    for (int r = 0; r < 4; ++r) {
        acc[r][0] = bb.x; acc[r][1] = bb.y; acc[r][2] = bb.z; acc[r][3] = bb.w;
    }

#pragma unroll
    for (int i = 0; i < 4; ++i) {
        int idx = tid + 256 * i;   // 0..1023
        int r = idx >> 4;          // row 0..63
        int c4 = idx & 15;
        int grow = rowBase + r;
        if (grow >= NN) grow = NN - 1;
        int c4s = c4 ^ ((r >> 2) & 3);
        *(float4*)(as_ + r * 64 + c4s * 4) = *(const float4*)(agg + (size_t)grow * HD + c4 * 4);
        *(float4*)(hs + r * 64 + c4s * 4) = *(const float4*)(h + (size_t)grow * HD + c4 * 4);
    }
    __syncthreads();

#pragma unroll 2
    for (int k = 0; k < 64; k += 4) {
        int kq = k >> 2;
        float4 l0 = *(const float4*)(Wl + (size_t)(k + 0) * HD + cg * 4);
        float4 l1 = *(const float4*)(Wl + (size_t)(k + 1) * HD + cg * 4);
        float4 l2 = *(const float4*)(Wl + (size_t)(k + 2) * HD + cg * 4);
        float4 l3 = *(const float4*)(Wl + (size_t)(k + 3) * HD + cg * 4);
        float4 r0 = *(const float4*)(Wr + (size_t)(k + 0) * HD + cg * 4);
        float4 r1 = *(const float4*)(Wr + (size_t)(k + 1) * HD + cg * 4);
        float4 r2 = *(const float4*)(Wr + (size_t)(k + 2) * HD + cg * 4);
        float4 r3 = *(const float4*)(Wr + (size_t)(k + 3) * HD + cg * 4);
#pragma unroll
        for (int r = 0; r < 4; ++r) {
            int row = rg * 4 + r;
            int c4s = kq ^ ((row >> 2) & 3);
            float4 av = *(const float4*)(as_ + row * 64 + c4s * 4);
            float4 hv = *(const float4*)(hs + row * 64 + c4s * 4);
            acc[r][0] = fmaf(av.x, l0.x, acc[r][0]);
            acc[r][1] = fmaf(av.x, l0.y, acc[r][1]);
            acc[r][2] = fmaf(av.x, l0.z, acc[r][2]);
            acc[r][3] = fmaf(av.x, l0.w, acc[r][3]);
            acc[r][0] = fmaf(av.y, l1.x, acc[r][0]);
            acc[r][1] = fmaf(av.y, l1.y, acc[r][1]);
            acc[r][2] = fmaf(av.y, l1.z, acc[r][2]);
            acc[r][3] = fmaf(av.y, l1.w, acc[r][3]);
            acc[r][0] = fmaf(av.z, l2.x, acc[r][0]);
            acc[r][1] = fmaf(av.z, l2.y, acc[r][1]);
            acc[r][2] = fmaf(av.z, l2.z, acc[r][2]);
            acc[r][3] = fmaf(av.z, l2.w, acc[r][3]);
            acc[r][0] = fmaf(av.w, l3.x, acc[r][0]);
            acc[r][1] = fmaf(av.w, l3.y, acc[r][1]);
            acc[r][2] = fmaf(av.w, l3.z, acc[r][2]);
            acc[r][3] = fmaf(av.w, l3.w, acc[r][3]);
            acc[r][0] = fmaf(hv.x, r0.x, acc[r][0]);
            acc[r][1] = fmaf(hv.x, r0.y, acc[r][1]);
            acc[r][2] = fmaf(hv.x, r0.z, acc[r][2]);
            acc[r][3] = fmaf(hv.x, r0.w, acc[r][3]);
            acc[r][0] = fmaf(hv.y, r1.x, acc[r][0]);
            acc[r][1] = fmaf(hv.y, r1.y, acc[r][1]);
            acc[r][2] = fmaf(hv.y, r1.z, acc[r][2]);
            acc[r][3] = fmaf(hv.y, r1.w, acc[r][3]);
            acc[r][0] = fmaf(hv.z, r2.x, acc[r][0]);
            acc[r][1] = fmaf(hv.z, r2.y, acc[r][1]);
            acc[r][2] = fmaf(hv.z, r2.z, acc[r][2]);
            acc[r][3] = fmaf(hv.z, r2.w, acc[r][3]);
            acc[r][0] = fmaf(hv.w, r3.x, acc[r][0]);
            acc[r][1] = fmaf(hv.w, r3.y, acc[r][1]);
            acc[r][2] = fmaf(hv.w, r3.z, acc[r][2]);
            acc[r][3] = fmaf(hv.w, r3.w, acc[r][3]);
        }
    }

#pragma unroll
    for (int r = 0; r < 4; ++r) {
        int row = rowBase + rg * 4 + r;
        if (row < NN) {
            int lrow = rg * 4 + r;
            int c4s = cg ^ ((lrow >> 2) & 3);
            float4 ho = *(const float4*)(hs + lrow * 64 + c4s * 4);
            float4 o;
            float c0 = acc[r][0], c1 = acc[r][1], c2 = acc[r][2], c3 = acc[r][3];
            o.x = ho.x + (c0 > 0.f ? c0 : 0.f);
            o.y = ho.y + (c1 > 0.f ? c1 : 0.f);
            o.z = ho.z + (c2 > 0.f ? c2 : 0.f);
            o.w = ho.w + (c3 > 0.f ? c3 : 0.f);
            *(float4*)(h + (size_t)row * HD + cg * 4) = o;
        }
    }
}

// ---------------- Output GEMM: out = h @ Wout + b_out  [100000,64]x[64,256] ----------------

__global__ __launch_bounds__(256) void gemm_out_k(const float* __restrict__ h, const float* __restrict__ Wout,
                                                  const float* __restrict__ b_out, float* __restrict__ out) {
    __shared__ float hs[32 * 64];  // 8 KB
    int tid = threadIdx.x;
    int cg = tid & 63;       // cols 4*cg..4*cg+3 (0..255)
    int rg = tid >> 6;       // rows 8*rg..8*rg+7 (wave-uniform)
    int rowBase = blockIdx.x * 32;
#pragma unroll
    for (int i = 0; i < 2; ++i) {
        int idx = tid + 256 * i;  // 0..511
        int r = idx >> 4;
        int c4 = idx & 15;
        int grow = rowBase + r;
        if (grow >= NN) grow = NN - 1;
        *(float4*)(hs + r * 64 + c4 * 4) = *(const float4*)(h + (size_t)grow * HD + c4 * 4);
    }
    __syncthreads();

    float4 bb = *(const float4*)(b_out + cg * 4);
    float acc[8][4];
#pragma unroll
    for (int r = 0; r < 8; ++r) {
        acc[r][0] = bb.x; acc[r][1] = bb.y; acc[r][2] = bb.z; acc[r][3] = bb.w;
    }

#pragma unroll 2
    for (int k = 0; k < 64; k += 4) {
        float4 w0 = *(const float4*)(Wout + (size_t)(k + 0) * NC + cg * 4);
        float4 w1 = *(const float4*)(Wout + (size_t)(k + 1) * NC + cg * 4);
        float4 w2 = *(const float4*)(Wout + (size_t)(k + 2) * NC + cg * 4);
        float4 w3 = *(const float4*)(Wout + (size_t)(k + 3) * NC + cg * 4);
#pragma unroll
        for (int r = 0; r < 8; ++r) {
            float4 hv = *(const float4*)(hs + (rg * 8 + r) * 64 + k);
            acc[r][0] = fmaf(hv.x, w0.x, acc[r][0]);
            acc[r][1] = fmaf(hv.x, w0.y, acc[r][1]);
            acc[r][2] = fmaf(hv.x, w0.z, acc[r][2]);
            acc[r][3] = fmaf(hv.x, w0.w, acc[r][3]);
            acc[r][0] = fmaf(hv.y, w1.x, acc[r][0]);
            acc[r][1] = fmaf(hv.y, w1.y, acc[r][1]);
            acc[r][2] = fmaf(hv.y, w1.z, acc[r][2]);
            acc[r][3] = fmaf(hv.y, w1.w, acc[r][3]);
            acc[r][0] = fmaf(hv.z, w2.x, acc[r][0]);
            acc[r][1] = fmaf(hv.z, w2.y, acc[r][1]);
            acc[r][2] = fmaf(hv.z, w2.z, acc[r][2]);
            acc[r][3] = fmaf(hv.z, w2.w, acc[r][3]);
            acc[r][0] = fmaf(hv.w, w3.x, acc[r][0]);
            acc[r][1] = fmaf(hv.w, w3.y, acc[r][1]);
            acc[r][2] = fmaf(hv.w, w3.z, acc[r][2]);
            acc[r][3] = fmaf(hv.w, w3.w, acc[r][3]);
        }
    }
#pragma unroll
    for (int r = 0; r < 8; ++r) {
        int row = rowBase + rg * 8 + r;
        if (row < NN) {
            float4 o;
            o.x = acc[r][0]; o.y = acc[r][1]; o.z = acc[r][2]; o.w = acc[r][3];
            *(float4*)(out + (size_t)row * NC + cg * 4) = o;
        }
    }
}

extern "C" void kernel_launch(void* const* d_in, const int* in_sizes, int n_in,
                              void* d_out, int out_size, void* d_ws, size_t ws_size,
                              hipStream_t stream) {
    const float* x    = (const float*)d_in[0];
    const int*   ei   = (const int*)d_in[1];   // [2, E]: src then dst
    const float* Win  = (const float*)d_in[2];
    const float* b_in = (const float*)d_in[3];
    const float* Wl   = (const float*)d_in[4]; // [4,64,64]
    const float* bl   = (const float*)d_in[5]; // [4,64]
    const float* Wr   = (const float*)d_in[6]; // [4,64,64]
    const float* Wout = (const float*)d_in[7];
    const float* b_out= (const float*)d_in[8];
    float* out = (float*)d_out;

    const int* src = ei;
    const int* dst = ei + EE;

    // workspace layout (16B-aligned chunks)
    char* ws = (char*)d_ws;
    float* h        = (float*)ws;                         // 6.4M floats
    float* agg      = h + (size_t)NN * HD;                // 6.4M floats
    int*   rowptr   = (int*)(agg + (size_t)NN * HD);      // 100001 (pad to 100004)
    int*   csr      = rowptr + 100004;                    // 3.2M
    float* inv      = (float*)(csr + EE);                 // 100000
    int*   bucketptr= (int*)(inv + NN);                   // 392 (pad 400)

    // CSR-build scratch overlays on agg (dead until first aggregate):
    unsigned int* ebuf = (unsigned int*)agg;              // EE u32 (12.8 MB)
    int* hist  = (int*)agg + EE;                          // NEB*NB (611 KB)
    int* bboff = hist + NEB * NB;                         // NEB*NB (611 KB)

    part_count<<<NEB, 256, 0, stream>>>(dst, hist);
    bucket_ptr<<<1, 512, 0, stream>>>(hist, bucketptr);
    part_scan<<<NB, 512, 0, stream>>>(hist, bucketptr, bboff);
    part_scatter<<<NEB, 256, 0, stream>>>(src, dst, bboff, ebuf);
    bucket_fill2<<<NB, 256, 0, stream>>>(ebuf, bucketptr, rowptr, inv, csr);

    gemm_in<<<(NN + 127) / 128, 256, 0, stream>>>(x, Win, b_in, h);

    for (int i = 0; i < 4; ++i) {
        aggregate<<<NN / 4, 256, 0, stream>>>((const float4*)h, rowptr, csr, inv, (float4*)agg);
        layer_conv<<<(NN + 63) / 64, 256, 0, stream>>>(agg, h, Wl + (size_t)i * HD * HD,
                                                       Wr + (size_t)i * HD * HD, bl + (size_t)i * HD);
    }

    gemm_out_k<<<(NN + 31) / 32, 256, 0, stream>>>(h, Wout, b_out, out);
}

// Round 4
// 1042.533 us; speedup vs baseline: 1.4395x; 1.0494x over previous
//
#include <hip/hip_runtime.h>
#include <hip/hip_bf16.h>

#define NN 100000
#define EE 3200000
#define HD 64
#define NF 512
#define NC 256

// ---- bucketed CSR-build parameters ----
#define BSH 8                 // 256 nodes per bucket
#define NB 391                // ceil(NN/256)
#define EB 8192               // edges per partition block
#define NEB 391               // ceil(EE/EB)

typedef __attribute__((ext_vector_type(8))) short bf16x8;
typedef __attribute__((ext_vector_type(4))) float f32x4;

__device__ __forceinline__ unsigned short f2bf(float f) {
    unsigned u = __float_as_uint(f);
    return (unsigned short)((u + 0x7FFFu + ((u >> 16) & 1u)) >> 16);  // RNE
}
__device__ __forceinline__ unsigned pack2(float a, float b) {
    return (unsigned)f2bf(a) | ((unsigned)f2bf(b) << 16);
}

// ---------------- bucketed edge partition ----------------
// Phase 1: per-(edge-block, bucket) histogram via LDS atomics.

__global__ __launch_bounds__(256) void part_count(const int* __restrict__ dst, int* __restrict__ hist) {
    __shared__ int hs[NB];
    int t = threadIdx.x, blk = blockIdx.x;
    for (int b = t; b < NB; b += 256) hs[b] = 0;
    __syncthreads();
    int base = blk * EB;
#pragma unroll
    for (int i = 0; i < EB / 256; ++i) {
        int e = base + t + 256 * i;
        if (e < EE) atomicAdd(&hs[dst[e] >> BSH], 1);
    }
    __syncthreads();
    for (int b = t; b < NB; b += 256) hist[blk * NB + b] = hs[b];
}

// Phase 1b: per-bucket totals + exclusive scan -> bucketptr[NB+1].

__global__ __launch_bounds__(512) void bucket_ptr(const int* __restrict__ hist, int* __restrict__ bucketptr) {
    __shared__ int s[512];
    int t = threadIdx.x;
    int v = 0;
    if (t < NB) {
        for (int blk = 0; blk < NEB; ++blk) v += hist[blk * NB + t];
    }
    s[t] = v; __syncthreads();
    for (int d = 1; d < 512; d <<= 1) {
        int a = (t >= d) ? s[t - d] : 0;
        __syncthreads();
        s[t] += a;
        __syncthreads();
    }
    if (t < NB) bucketptr[t] = s[t] - v;  // exclusive
    if (t == 0) bucketptr[NB] = EE;
}

// Phase 2: per-bucket exclusive scan over edge-blocks, anchored at bucketptr[b].

__global__ __launch_bounds__(512) void part_scan(const int* __restrict__ hist, const int* __restrict__ bucketptr,
                                                 int* __restrict__ bboff) {
    __shared__ int s[512];
    int b = blockIdx.x, t = threadIdx.x;
    int v = (t < NEB) ? hist[t * NB + b] : 0;
    s[t] = v; __syncthreads();
    for (int d = 1; d < 512; d <<= 1) {
        int a = (t >= d) ? s[t - d] : 0;
        __syncthreads();
        s[t] += a;
        __syncthreads();
    }
    if (t < NEB) bboff[t * NB + b] = bucketptr[b] + s[t] - v;  // exclusive
}

// Phase 3: scatter packed (src | dstLocal<<17) into bucket-grouped runs.

__global__ __launch_bounds__(256) void part_scatter(const int* __restrict__ src, const int* __restrict__ dst,
                                                    const int* __restrict__ bboff, unsigned int* __restrict__ ebuf) {
    __shared__ int off[NB];
    __shared__ int rank[NB];
    int t = threadIdx.x, blk = blockIdx.x;
    for (int b = t; b < NB; b += 256) { off[b] = bboff[blk * NB + b]; rank[b] = 0; }
    __syncthreads();
    int base = blk * EB;
#pragma unroll
    for (int i = 0; i < EB / 256; ++i) {
        int e = base + t + 256 * i;
        if (e < EE) {
            int d = dst[e];
            int s = src[e];
            int b = d >> BSH;
            int r = atomicAdd(&rank[b], 1);
            ebuf[off[b] + r] = (unsigned)s | ((unsigned)(d & 255) << 17);
        }
    }
}

// Phase 4: per-bucket node histogram + scan -> rowptr & inv, then scatter to csr.

__global__ __launch_bounds__(256) void bucket_fill2(const unsigned int* __restrict__ ebuf,
                                                    const int* __restrict__ bucketptr,
                                                    int* __restrict__ rowptr, float* __restrict__ inv,
                                                    int* __restrict__ csr) {
    __shared__ int hcnt[256];
    __shared__ int scn[256];
    __shared__ int cur[256];
    int t = threadIdx.x, b = blockIdx.x;
    int n0 = b << BSH;
    hcnt[t] = 0;
    __syncthreads();
    int estart = bucketptr[b];
    int eend = bucketptr[b + 1];
    for (int e = estart + t; e < eend; e += 256) {
        atomicAdd(&hcnt[ebuf[e] >> 17], 1);
    }
    __syncthreads();
    int v = hcnt[t];
    scn[t] = v;
    __syncthreads();
    for (int d = 1; d < 256; d <<= 1) {
        int a = (t >= d) ? scn[t - d] : 0;
        __syncthreads();
        scn[t] += a;
        __syncthreads();
    }
    int off = estart + scn[t] - v;  // exclusive within bucket
    cur[t] = off;
    if (n0 + t < NN) {
        rowptr[n0 + t] = off;
        inv[n0 + t] = 1.0f / (float)(v > 1 ? v : 1);
    }
    if (b == NB - 1 && t == 0) rowptr[NN] = EE;
    __syncthreads();
    for (int e = estart + t; e < eend; e += 256) {
        unsigned u = ebuf[e];
        int dL = (int)(u >> 17);
        int p = atomicAdd(&cur[dL], 1);
        csr[p] = (int)(u & 0x1FFFFu);
    }
}

// ---------------- Win -> bf16 fragment-packed ----------------
// wpk[t][c][lane][j] = bf16(Win[t*32 + (lane>>4)*8 + j][c*16 + (lane&15)])
// t = K-step (0..15, 32 k each), c = col-frag (0..3). 64 KB total, L2-resident.

__global__ __launch_bounds__(256) void pack_w(const float* __restrict__ Win, unsigned short* __restrict__ wpk) {
    int id = blockIdx.x * 256 + threadIdx.x;  // 0..4095
    int l = id & 63;
    int c = (id >> 6) & 3;
    int t = id >> 8;
    int kbase = t * 32 + (l >> 4) * 8;
    int col = c * 16 + (l & 15);
    float f[8];
#pragma unroll
    for (int j = 0; j < 8; ++j) f[j] = Win[(size_t)(kbase + j) * HD + col];
    uint4 p;
    p.x = pack2(f[0], f[1]); p.y = pack2(f[2], f[3]);
    p.z = pack2(f[4], f[5]); p.w = pack2(f[6], f[7]);
    *(uint4*)(wpk + (size_t)id * 8) = p;
}

// ---------------- GEMM: h = x @ Win + b_in via bf16 MFMA ----------------
// 128 rows x 64 cols per block, 4 waves; wave w = rows w*32..w*32+31 as 2x4
// 16x16 fragments, K-loop 512 in 64-k LDS tiles (two 32-k MFMA steps each).
// x staged as bf16 in LDS, 16B units XOR-swizzled by (row&7) (G4 fix for the
// 16-rows-same-column ds_read_b128 conflict). B-frags from wpk, 1 coalesced
// 16B load each. C/D mapping (m89): col=lane&15, row=(lane>>4)*4+reg.

__global__ __launch_bounds__(256) void gemm_in(const float* __restrict__ x, const unsigned short* __restrict__ wpk,
                                               const float* __restrict__ b_in, float* __restrict__ h) {
    __shared__ unsigned short xs[128 * 64];  // 16 KB bf16
    int tid = threadIdx.x;
    int lane = tid & 63;
    int w = tid >> 6;
    int rowBase = blockIdx.x * 128;
    int lr = lane & 15;   // row-in-frag (A) / col (C,D)
    int lg = lane >> 4;   // k-group / row-group (C,D)

    f32x4 acc[2][4];
#pragma unroll
    for (int c = 0; c < 4; ++c) {
        float bb = b_in[c * 16 + lr];
#pragma unroll
        for (int m = 0; m < 2; ++m) acc[m][c] = (f32x4){bb, bb, bb, bb};
    }

    for (int kt = 0; kt < NF; kt += 64) {  // 8 tiles
        __syncthreads();
#pragma unroll
        for (int i = 0; i < 4; ++i) {
            int idx = tid + 256 * i;   // 0..1023
            int r = idx >> 3;          // tile row 0..127
            int u = idx & 7;           // 16B unit (8 bf16) within row
            int grow = rowBase + r;
            if (grow >= NN) grow = NN - 1;
            const float* srcp = x + (size_t)grow * NF + kt + u * 8;
            float4 a = *(const float4*)(srcp);
            float4 b = *(const float4*)(srcp + 4);
            uint4 p;
            p.x = pack2(a.x, a.y); p.y = pack2(a.z, a.w);
            p.z = pack2(b.x, b.y); p.w = pack2(b.z, b.w);
            int u2 = u ^ (r & 7);
            *(uint4*)(xs + (size_t)r * 64 + u2 * 8) = p;
        }
        __syncthreads();
#pragma unroll
        for (int ks = 0; ks < 2; ++ks) {   // two 32-k MFMA steps
            int tstep = (kt >> 5) + ks;    // global K-step 0..15
            bf16x8 av[2], bv[4];
#pragma unroll
            for (int m = 0; m < 2; ++m) {
                int r = w * 32 + m * 16 + lr;
                int u2 = (ks * 4 + lg) ^ (r & 7);
                av[m] = *(const bf16x8*)(xs + (size_t)r * 64 + u2 * 8);
            }
#pragma unroll
            for (int c = 0; c < 4; ++c) {
                bv[c] = *(const bf16x8*)(wpk + (((size_t)tstep * 4 + c) * 64 + lane) * 8);
            }
#pragma unroll
            for (int m = 0; m < 2; ++m)
#pragma unroll
                for (int c = 0; c < 4; ++c)
                    acc[m][c] = __builtin_amdgcn_mfma_f32_16x16x32_bf16(av[m], bv[c], acc[m][c], 0, 0, 0);
        }
    }

#pragma unroll
    for (int m = 0; m < 2; ++m) {
        int rbase = rowBase + w * 32 + m * 16 + lg * 4;
#pragma unroll
        for (int j = 0; j < 4; ++j) {
            int row = rbase + j;
            if (row < NN) {
#pragma unroll
                for (int c = 0; c < 4; ++c)
                    h[(size_t)row * HD + c * 16 + lr] = acc[m][c][j];
            }
        }
    }
}

// ---------------- Aggregation: agg[n] = mean over in-edges of h[src] ----------------

__global__ __launch_bounds__(256) void aggregate(const float4* __restrict__ h4, const int* __restrict__ rowptr,
                                                 const int* __restrict__ csr, const float* __restrict__ inv,
                                                 float4* __restrict__ agg4) {
    int tid = threadIdx.x;
    int lane = tid & 63;
    int q = lane >> 4;
    int f = lane & 15;
    int node = blockIdx.x * 4 + (tid >> 6);
    int n = __builtin_amdgcn_readfirstlane(node);
    int start = rowptr[n];
    int end = rowptr[n + 1];

    float4 acc0 = make_float4(0.f, 0.f, 0.f, 0.f);
    float4 acc1 = make_float4(0.f, 0.f, 0.f, 0.f);
    int e = start;
    int end8 = start + ((end - start) & ~7);
    for (; e < end8; e += 8) {
        int s0 = csr[e + q];
        int s1 = csr[e + 4 + q];
        float4 v0 = h4[(size_t)s0 * 16 + f];
        float4 v1 = h4[(size_t)s1 * 16 + f];
        acc0.x += v0.x; acc0.y += v0.y; acc0.z += v0.z; acc0.w += v0.w;
        acc1.x += v1.x; acc1.y += v1.y; acc1.z += v1.z; acc1.w += v1.w;
    }
    if (e + q < end) {
        int s = csr[e + q];
        float4 v = h4[(size_t)s * 16 + f];
        acc0.x += v.x; acc0.y += v.y; acc0.z += v.z; acc0.w += v.w;
    }
    e += 4;
    if (e + q < end) {
        int s = csr[e + q];
        float4 v = h4[(size_t)s * 16 + f];
        acc1.x += v.x; acc1.y += v.y; acc1.z += v.z; acc1.w += v.w;
    }

    float4 a;
    a.x = acc0.x + acc1.x;
    a.y = acc0.y + acc1.y;
    a.z = acc0.z + acc1.z;
    a.w = acc0.w + acc1.w;
    a.x += __shfl_xor(a.x, 16); a.x += __shfl_xor(a.x, 32);
    a.y += __shfl_xor(a.y, 16); a.y += __shfl_xor(a.y, 32);
    a.z += __shfl_xor(a.z, 16); a.z += __shfl_xor(a.z, 32);
    a.w += __shfl_xor(a.w, 16); a.w += __shfl_xor(a.w, 32);

    if (q == 0) {
        float s = inv[n];
        float4 r;
        r.x = a.x * s; r.y = a.y * s; r.z = a.z * s; r.w = a.w * s;
        agg4[(size_t)n * 16 + f] = r;
    }
}

// ---------------- Layer: h = h + relu(agg@Wl + bl + h@Wr) ----------------

__global__ __launch_bounds__(256) void layer_conv(const float* __restrict__ agg, float* __restrict__ h,
                                                  const float* __restrict__ Wl, const float* __restrict__ Wr,
                                                  const float* __restrict__ bl) {
    __shared__ float as_[64 * 64];  // 16 KB
    __shared__ float hs[64 * 64];   // 16 KB
    int tid = threadIdx.x;
    int cg = tid & 15;      // cols 4*cg..4*cg+3
    int rg = tid >> 4;      // rows 4*rg..4*rg+3
    int rowBase = blockIdx.x * 64;
    float4 bb = *(const float4*)(bl + cg * 4);
    float acc[4][4];
#pragma unroll
    for (int r = 0; r < 4; ++r) {
        acc[r][0] = bb.x; acc[r][1] = bb.y; acc[r][2] = bb.z; acc[r][3] = bb.w;
    }

#pragma unroll
    for (int i = 0; i < 4; ++i) {
        int idx = tid + 256 * i;   // 0..1023
        int r = idx >> 4;          // row 0..63
        int c4 = idx & 15;
        int grow = rowBase + r;
        if (grow >= NN) grow = NN - 1;
        int c4s = c4 ^ ((r >> 2) & 3);
        *(float4*)(as_ + r * 64 + c4s * 4) = *(const float4*)(agg + (size_t)grow * HD + c4 * 4);
        *(float4*)(hs + r * 64 + c4s * 4) = *(const float4*)(h + (size_t)grow * HD + c4 * 4);
    }
    __syncthreads();

#pragma unroll 2
    for (int k = 0; k < 64; k += 4) {
        int kq = k >> 2;
        float4 l0 = *(const float4*)(Wl + (size_t)(k + 0) * HD + cg * 4);
        float4 l1 = *(const float4*)(Wl + (size_t)(k + 1) * HD + cg * 4);
        float4 l2 = *(const float4*)(Wl + (size_t)(k + 2) * HD + cg * 4);
        float4 l3 = *(const float4*)(Wl + (size_t)(k + 3) * HD + cg * 4);
        float4 r0 = *(const float4*)(Wr + (size_t)(k + 0) * HD + cg * 4);
        float4 r1 = *(const float4*)(Wr + (size_t)(k + 1) * HD + cg * 4);
        float4 r2 = *(const float4*)(Wr + (size_t)(k + 2) * HD + cg * 4);
        float4 r3 = *(const float4*)(Wr + (size_t)(k + 3) * HD + cg * 4);
#pragma unroll
        for (int r = 0; r < 4; ++r) {
            int row = rg * 4 + r;
            int c4s = kq ^ ((row >> 2) & 3);
            float4 av = *(const float4*)(as_ + row * 64 + c4s * 4);
            float4 hv = *(const float4*)(hs + row * 64 + c4s * 4);
            acc[r][0] = fmaf(av.x, l0.x, acc[r][0]);
            acc[r][1] = fmaf(av.x, l0.y, acc[r][1]);
            acc[r][2] = fmaf(av.x, l0.z, acc[r][2]);
            acc[r][3] = fmaf(av.x, l0.w, acc[r][3]);
            acc[r][0] = fmaf(av.y, l1.x, acc[r][0]);
            acc[r][1] = fmaf(av.y, l1.y, acc[r][1]);
            acc[r][2] = fmaf(av.y, l1.z, acc[r][2]);
            acc[r][3] = fmaf(av.y, l1.w, acc[r][3]);
            acc[r][0] = fmaf(av.z, l2.x, acc[r][0]);
            acc[r][1] = fmaf(av.z, l2.y, acc[r][1]);
            acc[r][2] = fmaf(av.z, l2.z, acc[r][2]);
            acc[r][3] = fmaf(av.z, l2.w, acc[r][3]);
            acc[r][0] = fmaf(av.w, l3.x, acc[r][0]);
            acc[r][1] = fmaf(av.w, l3.y, acc[r][1]);
            acc[r][2] = fmaf(av.w, l3.z, acc[r][2]);
            acc[r][3] = fmaf(av.w, l3.w, acc[r][3]);
            acc[r][0] = fmaf(hv.x, r0.x, acc[r][0]);
            acc[r][1] = fmaf(hv.x, r0.y, acc[r][1]);
            acc[r][2] = fmaf(hv.x, r0.z, acc[r][2]);
            acc[r][3] = fmaf(hv.x, r0.w, acc[r][3]);
            acc[r][0] = fmaf(hv.y, r1.x, acc[r][0]);
            acc[r][1] = fmaf(hv.y, r1.y, acc[r][1]);
            acc[r][2] = fmaf(hv.y, r1.z, acc[r][2]);
            acc[r][3] = fmaf(hv.y, r1.w, acc[r][3]);
            acc[r][0] = fmaf(hv.z, r2.x, acc[r][0]);
            acc[r][1] = fmaf(hv.z, r2.y, acc[r][1]);
            acc[r][2] = fmaf(hv.z, r2.z, acc[r][2]);
            acc[r][3] = fmaf(hv.z, r2.w, acc[r][3]);
            acc[r][0] = fmaf(hv.w, r3.x, acc[r][0]);
            acc[r][1] = fmaf(hv.w, r3.y, acc[r][1]);
            acc[r][2] = fmaf(hv.w, r3.z, acc[r][2]);
            acc[r][3] = fmaf(hv.w, r3.w, acc[r][3]);
        }
    }

#pragma unroll
    for (int r = 0; r < 4; ++r) {
        int row = rowBase + rg * 4 + r;
        if (row < NN) {
            int lrow = rg * 4 + r;
            int c4s = cg ^ ((lrow >> 2) & 3);
            float4 ho = *(const float4*)(hs + lrow * 64 + c4s * 4);
            float4 o;
            float c0 = acc[r][0], c1 = acc[r][1], c2 = acc[r][2], c3 = acc[r][3];
            o.x = ho.x + (c0 > 0.f ? c0 : 0.f);
            o.y = ho.y + (c1 > 0.f ? c1 : 0.f);
            o.z = ho.z + (c2 > 0.f ? c2 : 0.f);
            o.w = ho.w + (c3 > 0.f ? c3 : 0.f);
            *(float4*)(h + (size_t)row * HD + cg * 4) = o;
        }
    }
}

// ---------------- Output GEMM: out = h @ Wout + b_out  [100000,64]x[64,256] ----------------

__global__ __launch_bounds__(256) void gemm_out_k(const float* __restrict__ h, const float* __restrict__ Wout,
                                                  const float* __restrict__ b_out, float* __restrict__ out) {
    __shared__ float hs[32 * 64];  // 8 KB
    int tid = threadIdx.x;
    int cg = tid & 63;       // cols 4*cg..4*cg+3 (0..255)
    int rg = tid >> 6;       // rows 8*rg..8*rg+7 (wave-uniform)
    int rowBase = blockIdx.x * 32;
#pragma unroll
    for (int i = 0; i < 2; ++i) {
        int idx = tid + 256 * i;  // 0..511
        int r = idx >> 4;
        int c4 = idx & 15;
        int grow = rowBase + r;
        if (grow >= NN) grow = NN - 1;
        *(float4*)(hs + r * 64 + c4 * 4) = *(const float4*)(h + (size_t)grow * HD + c4 * 4);
    }
    __syncthreads();

    float4 bb = *(const float4*)(b_out + cg * 4);
    float acc[8][4];
#pragma unroll
    for (int r = 0; r < 8; ++r) {
        acc[r][0] = bb.x; acc[r][1] = bb.y; acc[r][2] = bb.z; acc[r][3] = bb.w;
    }

#pragma unroll 2
    for (int k = 0; k < 64; k += 4) {
        float4 w0 = *(const float4*)(Wout + (size_t)(k + 0) * NC + cg * 4);
        float4 w1 = *(const float4*)(Wout + (size_t)(k + 1) * NC + cg * 4);
        float4 w2 = *(const float4*)(Wout + (size_t)(k + 2) * NC + cg * 4);
        float4 w3 = *(const float4*)(Wout + (size_t)(k + 3) * NC + cg * 4);
#pragma unroll
        for (int r = 0; r < 8; ++r) {
            float4 hv = *(const float4*)(hs + (rg * 8 + r) * 64 + k);
            acc[r][0] = fmaf(hv.x, w0.x, acc[r][0]);
            acc[r][1] = fmaf(hv.x, w0.y, acc[r][1]);
            acc[r][2] = fmaf(hv.x, w0.z, acc[r][2]);
            acc[r][3] = fmaf(hv.x, w0.w, acc[r][3]);
            acc[r][0] = fmaf(hv.y, w1.x, acc[r][0]);
            acc[r][1] = fmaf(hv.y, w1.y, acc[r][1]);
            acc[r][2] = fmaf(hv.y, w1.z, acc[r][2]);
            acc[r][3] = fmaf(hv.y, w1.w, acc[r][3]);
            acc[r][0] = fmaf(hv.z, w2.x, acc[r][0]);
            acc[r][1] = fmaf(hv.z, w2.y, acc[r][1]);
            acc[r][2] = fmaf(hv.z, w2.z, acc[r][2]);
            acc[r][3] = fmaf(hv.z, w2.w, acc[r][3]);
            acc[r][0] = fmaf(hv.w, w3.x, acc[r][0]);
            acc[r][1] = fmaf(hv.w, w3.y, acc[r][1]);
            acc[r][2] = fmaf(hv.w, w3.z, acc[r][2]);
            acc[r][3] = fmaf(hv.w, w3.w, acc[r][3]);
        }
    }
#pragma unroll
    for (int r = 0; r < 8; ++r) {
        int row = rowBase + rg * 8 + r;
        if (row < NN) {
            float4 o;
            o.x = acc[r][0]; o.y = acc[r][1]; o.z = acc[r][2]; o.w = acc[r][3];
            *(float4*)(out + (size_t)row * NC + cg * 4) = o;
        }
    }
}

extern "C" void kernel_launch(void* const* d_in, const int* in_sizes, int n_in,
                              void* d_out, int out_size, void* d_ws, size_t ws_size,
                              hipStream_t stream) {
    const float* x    = (const float*)d_in[0];
    const int*   ei   = (const int*)d_in[1];   // [2, E]: src then dst
    const float* Win  = (const float*)d_in[2];
    const float* b_in = (const float*)d_in[3];
    const float* Wl   = (const float*)d_in[4]; // [4,64,64]
    const float* bl   = (const float*)d_in[5]; // [4,64]
    const float* Wr   = (const float*)d_in[6]; // [4,64,64]
    const float* Wout = (const float*)d_in[7];
    const float* b_out= (const float*)d_in[8];
    float* out = (float*)d_out;

    const int* src = ei;
    const int* dst = ei + EE;

    // workspace layout (16B-aligned chunks)
    char* ws = (char*)d_ws;
    float* h        = (float*)ws;                         // 6.4M floats
    float* agg      = h + (size_t)NN * HD;                // 6.4M floats
    int*   rowptr   = (int*)(agg + (size_t)NN * HD);      // 100001 (pad to 100004)
    int*   csr      = rowptr + 100004;                    // 3.2M
    float* inv      = (float*)(csr + EE);                 // 100000
    int*   bucketptr= (int*)(inv + NN);                   // 392 (pad 400)
    unsigned short* wpk = (unsigned short*)(bucketptr + 400);  // 32768 (64 KB)

    // CSR-build scratch overlays on agg (dead until first aggregate):
    unsigned int* ebuf = (unsigned int*)agg;              // EE u32 (12.8 MB)
    int* hist  = (int*)agg + EE;                          // NEB*NB (611 KB)
    int* bboff = hist + NEB * NB;                         // NEB*NB (611 KB)

    pack_w<<<16, 256, 0, stream>>>(Win, wpk);

    part_count<<<NEB, 256, 0, stream>>>(dst, hist);
    bucket_ptr<<<1, 512, 0, stream>>>(hist, bucketptr);
    part_scan<<<NB, 512, 0, stream>>>(hist, bucketptr, bboff);
    part_scatter<<<NEB, 256, 0, stream>>>(src, dst, bboff, ebuf);
    bucket_fill2<<<NB, 256, 0, stream>>>(ebuf, bucketptr, rowptr, inv, csr);

    gemm_in<<<(NN + 127) / 128, 256, 0, stream>>>(x, wpk, b_in, h);

    for (int i = 0; i < 4; ++i) {
        aggregate<<<NN / 4, 256, 0, stream>>>((const float4*)h, rowptr, csr, inv, (float4*)agg);
        layer_conv<<<(NN + 63) / 64, 256, 0, stream>>>(agg, h, Wl + (size_t)i * HD * HD,
                                                       Wr + (size_t)i * HD * HD, bl + (size_t)i * HD);
    }

    gemm_out_k<<<(NN + 31) / 32, 256, 0, stream>>>(h, Wout, b_out, out);
}

// Round 5
// 1003.650 us; speedup vs baseline: 1.4952x; 1.0387x over previous
//
#include <hip/hip_runtime.h>
#include <hip/hip_bf16.h>

#define NN 100000
#define EE 3200000
#define HD 64
#define NF 512
#define NC 256

// ---- bucketed CSR-build parameters ----
#define BSH 8                 // 256 nodes per bucket
#define NB 391                // ceil(NN/256)
#define EB 8192               // edges per partition block
#define NEB 391               // ceil(EE/EB)

typedef __attribute__((ext_vector_type(8))) short bf16x8;
typedef __attribute__((ext_vector_type(4))) float f32x4;
typedef __attribute__((ext_vector_type(4))) unsigned short u16x4;

__device__ __forceinline__ unsigned short f2bf(float f) {
    unsigned u = __float_as_uint(f);
    return (unsigned short)((u + 0x7FFFu + ((u >> 16) & 1u)) >> 16);  // RNE
}
__device__ __forceinline__ unsigned pack2(float a, float b) {
    return (unsigned)f2bf(a) | ((unsigned)f2bf(b) << 16);
}
__device__ __forceinline__ float bf2f(unsigned short v) {
    return __uint_as_float(((unsigned)v) << 16);
}

// ---------------- bucketed edge partition ----------------
// Phase 1: per-(edge-block, bucket) histogram via LDS atomics.

__global__ __launch_bounds__(256) void part_count(const int* __restrict__ dst, int* __restrict__ hist) {
    __shared__ int hs[NB];
    int t = threadIdx.x, blk = blockIdx.x;
    for (int b = t; b < NB; b += 256) hs[b] = 0;
    __syncthreads();
    int base = blk * EB;
#pragma unroll
    for (int i = 0; i < EB / 256; ++i) {
        int e = base + t + 256 * i;
        if (e < EE) atomicAdd(&hs[dst[e] >> BSH], 1);
    }
    __syncthreads();
    for (int b = t; b < NB; b += 256) hist[blk * NB + b] = hs[b];
}

// Phase 1b: per-bucket totals + exclusive scan -> bucketptr[NB+1].

__global__ __launch_bounds__(512) void bucket_ptr(const int* __restrict__ hist, int* __restrict__ bucketptr) {
    __shared__ int s[512];
    int t = threadIdx.x;
    int v = 0;
    if (t < NB) {
        for (int blk = 0; blk < NEB; ++blk) v += hist[blk * NB + t];
    }
    s[t] = v; __syncthreads();
    for (int d = 1; d < 512; d <<= 1) {
        int a = (t >= d) ? s[t - d] : 0;
        __syncthreads();
        s[t] += a;
        __syncthreads();
    }
    if (t < NB) bucketptr[t] = s[t] - v;  // exclusive
    if (t == 0) bucketptr[NB] = EE;
}

// Phase 2: per-bucket exclusive scan over edge-blocks, anchored at bucketptr[b].

__global__ __launch_bounds__(512) void part_scan(const int* __restrict__ hist, const int* __restrict__ bucketptr,
                                                 int* __restrict__ bboff) {
    __shared__ int s[512];
    int b = blockIdx.x, t = threadIdx.x;
    int v = (t < NEB) ? hist[t * NB + b] : 0;
    s[t] = v; __syncthreads();
    for (int d = 1; d < 512; d <<= 1) {
        int a = (t >= d) ? s[t - d] : 0;
        __syncthreads();
        s[t] += a;
        __syncthreads();
    }
    if (t < NEB) bboff[t * NB + b] = bucketptr[b] + s[t] - v;  // exclusive
}

// Phase 3: scatter packed (src | dstLocal<<17) into bucket-grouped runs.

__global__ __launch_bounds__(256) void part_scatter(const int* __restrict__ src, const int* __restrict__ dst,
                                                    const int* __restrict__ bboff, unsigned int* __restrict__ ebuf) {
    __shared__ int off[NB];
    __shared__ int rank[NB];
    int t = threadIdx.x, blk = blockIdx.x;
    for (int b = t; b < NB; b += 256) { off[b] = bboff[blk * NB + b]; rank[b] = 0; }
    __syncthreads();
    int base = blk * EB;
#pragma unroll
    for (int i = 0; i < EB / 256; ++i) {
        int e = base + t + 256 * i;
        if (e < EE) {
            int d = dst[e];
            int s = src[e];
            int b = d >> BSH;
            int r = atomicAdd(&rank[b], 1);
            ebuf[off[b] + r] = (unsigned)s | ((unsigned)(d & 255) << 17);
        }
    }
}

// Phase 4: per-bucket node histogram + scan -> rowptr & inv, then scatter to csr.

__global__ __launch_bounds__(256) void bucket_fill2(const unsigned int* __restrict__ ebuf,
                                                    const int* __restrict__ bucketptr,
                                                    int* __restrict__ rowptr, float* __restrict__ inv,
                                                    int* __restrict__ csr) {
    __shared__ int hcnt[256];
    __shared__ int scn[256];
    __shared__ int cur[256];
    int t = threadIdx.x, b = blockIdx.x;
    int n0 = b << BSH;
    hcnt[t] = 0;
    __syncthreads();
    int estart = bucketptr[b];
    int eend = bucketptr[b + 1];
    for (int e = estart + t; e < eend; e += 256) {
        atomicAdd(&hcnt[ebuf[e] >> 17], 1);
    }
    __syncthreads();
    int v = hcnt[t];
    scn[t] = v;
    __syncthreads();
    for (int d = 1; d < 256; d <<= 1) {
        int a = (t >= d) ? scn[t - d] : 0;
        __syncthreads();
        scn[t] += a;
        __syncthreads();
    }
    int off = estart + scn[t] - v;  // exclusive within bucket
    cur[t] = off;
    if (n0 + t < NN) {
        rowptr[n0 + t] = off;
        inv[n0 + t] = 1.0f / (float)(v > 1 ? v : 1);
    }
    if (b == NB - 1 && t == 0) rowptr[NN] = EE;
    __syncthreads();
    for (int e = estart + t; e < eend; e += 256) {
        unsigned u = ebuf[e];
        int dL = (int)(u >> 17);
        int p = atomicAdd(&cur[dL], 1);
        csr[p] = (int)(u & 0x1FFFFu);
    }
}

// ---------------- Win -> bf16 fragment-packed ----------------
// wpk[t][c][lane][j] = bf16(Win[t*32 + (lane>>4)*8 + j][c*16 + (lane&15)])

__global__ __launch_bounds__(256) void pack_w(const float* __restrict__ Win, unsigned short* __restrict__ wpk) {
    int id = blockIdx.x * 256 + threadIdx.x;  // 0..4095
    int l = id & 63;
    int c = (id >> 6) & 3;
    int t = id >> 8;
    int kbase = t * 32 + (l >> 4) * 8;
    int col = c * 16 + (l & 15);
    float f[8];
#pragma unroll
    for (int j = 0; j < 8; ++j) f[j] = Win[(size_t)(kbase + j) * HD + col];
    uint4 p;
    p.x = pack2(f[0], f[1]); p.y = pack2(f[2], f[3]);
    p.z = pack2(f[4], f[5]); p.w = pack2(f[6], f[7]);
    *(uint4*)(wpk + (size_t)id * 8) = p;
}

// ---------------- GEMM: h = x @ Win + b_in via bf16 MFMA ----------------
// Also writes bf16 mirror h_bf for the aggregation gather.

__global__ __launch_bounds__(256) void gemm_in(const float* __restrict__ x, const unsigned short* __restrict__ wpk,
                                               const float* __restrict__ b_in, float* __restrict__ h,
                                               unsigned short* __restrict__ hb) {
    __shared__ unsigned short xs[128 * 64];  // 16 KB bf16
    int tid = threadIdx.x;
    int lane = tid & 63;
    int w = tid >> 6;
    int rowBase = blockIdx.x * 128;
    int lr = lane & 15;   // row-in-frag (A) / col (C,D)
    int lg = lane >> 4;   // k-group / row-group (C,D)

    f32x4 acc[2][4];
#pragma unroll
    for (int c = 0; c < 4; ++c) {
        float bb = b_in[c * 16 + lr];
#pragma unroll
        for (int m = 0; m < 2; ++m) acc[m][c] = (f32x4){bb, bb, bb, bb};
    }

    for (int kt = 0; kt < NF; kt += 64) {  // 8 tiles
        __syncthreads();
#pragma unroll
        for (int i = 0; i < 4; ++i) {
            int idx = tid + 256 * i;   // 0..1023
            int r = idx >> 3;          // tile row 0..127
            int u = idx & 7;           // 16B unit (8 bf16) within row
            int grow = rowBase + r;
            if (grow >= NN) grow = NN - 1;
            const float* srcp = x + (size_t)grow * NF + kt + u * 8;
            float4 a = *(const float4*)(srcp);
            float4 b = *(const float4*)(srcp + 4);
            uint4 p;
            p.x = pack2(a.x, a.y); p.y = pack2(a.z, a.w);
            p.z = pack2(b.x, b.y); p.w = pack2(b.z, b.w);
            int u2 = u ^ (r & 7);
            *(uint4*)(xs + (size_t)r * 64 + u2 * 8) = p;
        }
        __syncthreads();
#pragma unroll
        for (int ks = 0; ks < 2; ++ks) {   // two 32-k MFMA steps
            int tstep = (kt >> 5) + ks;    // global K-step 0..15
            bf16x8 av[2], bv[4];
#pragma unroll
            for (int m = 0; m < 2; ++m) {
                int r = w * 32 + m * 16 + lr;
                int u2 = (ks * 4 + lg) ^ (r & 7);
                av[m] = *(const bf16x8*)(xs + (size_t)r * 64 + u2 * 8);
            }
#pragma unroll
            for (int c = 0; c < 4; ++c) {
                bv[c] = *(const bf16x8*)(wpk + (((size_t)tstep * 4 + c) * 64 + lane) * 8);
            }
#pragma unroll
            for (int m = 0; m < 2; ++m)
#pragma unroll
                for (int c = 0; c < 4; ++c)
                    acc[m][c] = __builtin_amdgcn_mfma_f32_16x16x32_bf16(av[m], bv[c], acc[m][c], 0, 0, 0);
        }
    }

#pragma unroll
    for (int m = 0; m < 2; ++m) {
        int rbase = rowBase + w * 32 + m * 16 + lg * 4;
#pragma unroll
        for (int j = 0; j < 4; ++j) {
            int row = rbase + j;
            if (row < NN) {
#pragma unroll
                for (int c = 0; c < 4; ++c) {
                    float v = acc[m][c][j];
                    h[(size_t)row * HD + c * 16 + lr] = v;
                    hb[(size_t)row * HD + c * 16 + lr] = f2bf(v);
                }
            }
        }
    }
}

// ---------------- Aggregation: agg[n] = mean over in-edges of h_bf[src] ----------------
// Gathers bf16 rows (128 B/edge instead of 256 B), accumulates fp32.

__global__ __launch_bounds__(256) void aggregate(const unsigned short* __restrict__ hb, const int* __restrict__ rowptr,
                                                 const int* __restrict__ csr, const float* __restrict__ inv,
                                                 float4* __restrict__ agg4) {
    int tid = threadIdx.x;
    int lane = tid & 63;
    int q = lane >> 4;
    int f = lane & 15;
    int node = blockIdx.x * 4 + (tid >> 6);
    int n = __builtin_amdgcn_readfirstlane(node);
    int start = rowptr[n];
    int end = rowptr[n + 1];

    float4 acc0 = make_float4(0.f, 0.f, 0.f, 0.f);
    float4 acc1 = make_float4(0.f, 0.f, 0.f, 0.f);
    int e = start;
    int end8 = start + ((end - start) & ~7);
    for (; e < end8; e += 8) {
        int s0 = csr[e + q];
        int s1 = csr[e + 4 + q];
        u16x4 v0 = *(const u16x4*)(hb + (size_t)s0 * HD + f * 4);
        u16x4 v1 = *(const u16x4*)(hb + (size_t)s1 * HD + f * 4);
        acc0.x += bf2f(v0.x); acc0.y += bf2f(v0.y); acc0.z += bf2f(v0.z); acc0.w += bf2f(v0.w);
        acc1.x += bf2f(v1.x); acc1.y += bf2f(v1.y); acc1.z += bf2f(v1.z); acc1.w += bf2f(v1.w);
    }
    if (e + q < end) {
        int s = csr[e + q];
        u16x4 v = *(const u16x4*)(hb + (size_t)s * HD + f * 4);
        acc0.x += bf2f(v.x); acc0.y += bf2f(v.y); acc0.z += bf2f(v.z); acc0.w += bf2f(v.w);
    }
    e += 4;
    if (e + q < end) {
        int s = csr[e + q];
        u16x4 v = *(const u16x4*)(hb + (size_t)s * HD + f * 4);
        acc1.x += bf2f(v.x); acc1.y += bf2f(v.y); acc1.z += bf2f(v.z); acc1.w += bf2f(v.w);
    }

    float4 a;
    a.x = acc0.x + acc1.x;
    a.y = acc0.y + acc1.y;
    a.z = acc0.z + acc1.z;
    a.w = acc0.w + acc1.w;
    a.x += __shfl_xor(a.x, 16); a.x += __shfl_xor(a.x, 32);
    a.y += __shfl_xor(a.y, 16); a.y += __shfl_xor(a.y, 32);
    a.z += __shfl_xor(a.z, 16); a.z += __shfl_xor(a.z, 32);
    a.w += __shfl_xor(a.w, 16); a.w += __shfl_xor(a.w, 32);

    if (q == 0) {
        float s = inv[n];
        float4 r;
        r.x = a.x * s; r.y = a.y * s; r.z = a.z * s; r.w = a.w * s;
        agg4[(size_t)n * 16 + f] = r;
    }
}

// ---------------- Layer: h = h + relu(agg@Wl + bl + h@Wr) ----------------
// Also refreshes the bf16 mirror h_bf.

__global__ __launch_bounds__(256) void layer_conv(const float* __restrict__ agg, float* __restrict__ h,
                                                  unsigned short* __restrict__ hb,
                                                  const float* __restrict__ Wl, const float* __restrict__ Wr,
                                                  const float* __restrict__ bl) {
    __shared__ float as_[64 * 64];  // 16 KB
    __shared__ float hs[64 * 64];   // 16 KB
    int tid = threadIdx.x;
    int cg = tid & 15;      // cols 4*cg..4*cg+3
    int rg = tid >> 4;      // rows 4*rg..4*rg+3
    int rowBase = blockIdx.x * 64;
    float4 bb = *(const float4*)(bl + cg * 4);
    float acc[4][4];
#pragma unroll
    for (int r = 0; r < 4; ++r) {
        acc[r][0] = bb.x; acc[r][1] = bb.y; acc[r][2] = bb.z; acc[r][3] = bb.w;
    }

#pragma unroll
    for (int i = 0; i < 4; ++i) {
        int idx = tid + 256 * i;   // 0..1023
        int r = idx >> 4;          // row 0..63
        int c4 = idx & 15;
        int grow = rowBase + r;
        if (grow >= NN) grow = NN - 1;
        int c4s = c4 ^ ((r >> 2) & 3);
        *(float4*)(as_ + r * 64 + c4s * 4) = *(const float4*)(agg + (size_t)grow * HD + c4 * 4);
        *(float4*)(hs + r * 64 + c4s * 4) = *(const float4*)(h + (size_t)grow * HD + c4 * 4);
    }
    __syncthreads();

#pragma unroll 2
    for (int k = 0; k < 64; k += 4) {
        int kq = k >> 2;
        float4 l0 = *(const float4*)(Wl + (size_t)(k + 0) * HD + cg * 4);
        float4 l1 = *(const float4*)(Wl + (size_t)(k + 1) * HD + cg * 4);
        float4 l2 = *(const float4*)(Wl + (size_t)(k + 2) * HD + cg * 4);
        float4 l3 = *(const float4*)(Wl + (size_t)(k + 3) * HD + cg * 4);
        float4 r0 = *(const float4*)(Wr + (size_t)(k + 0) * HD + cg * 4);
        float4 r1 = *(const float4*)(Wr + (size_t)(k + 1) * HD + cg * 4);
        float4 r2 = *(const float4*)(Wr + (size_t)(k + 2) * HD + cg * 4);
        float4 r3 = *(const float4*)(Wr + (size_t)(k + 3) * HD + cg * 4);
#pragma unroll
        for (int r = 0; r < 4; ++r) {
            int row = rg * 4 + r;
            int c4s = kq ^ ((row >> 2) & 3);
            float4 av = *(const float4*)(as_ + row * 64 + c4s * 4);
            float4 hv = *(const float4*)(hs + row * 64 + c4s * 4);
            acc[r][0] = fmaf(av.x, l0.x, acc[r][0]);
            acc[r][1] = fmaf(av.x, l0.y, acc[r][1]);
            acc[r][2] = fmaf(av.x, l0.z, acc[r][2]);
            acc[r][3] = fmaf(av.x, l0.w, acc[r][3]);
            acc[r][0] = fmaf(av.y, l1.x, acc[r][0]);
            acc[r][1] = fmaf(av.y, l1.y, acc[r][1]);
            acc[r][2] = fmaf(av.y, l1.z, acc[r][2]);
            acc[r][3] = fmaf(av.y, l1.w, acc[r][3]);
            acc[r][0] = fmaf(av.z, l2.x, acc[r][0]);
            acc[r][1] = fmaf(av.z, l2.y, acc[r][1]);
            acc[r][2] = fmaf(av.z, l2.z, acc[r][2]);
            acc[r][3] = fmaf(av.z, l2.w, acc[r][3]);
            acc[r][0] = fmaf(av.w, l3.x, acc[r][0]);
            acc[r][1] = fmaf(av.w, l3.y, acc[r][1]);
            acc[r][2] = fmaf(av.w, l3.z, acc[r][2]);
            acc[r][3] = fmaf(av.w, l3.w, acc[r][3]);
            acc[r][0] = fmaf(hv.x, r0.x, acc[r][0]);
            acc[r][1] = fmaf(hv.x, r0.y, acc[r][1]);
            acc[r][2] = fmaf(hv.x, r0.z, acc[r][2]);
            acc[r][3] = fmaf(hv.x, r0.w, acc[r][3]);
            acc[r][0] = fmaf(hv.y, r1.x, acc[r][0]);
            acc[r][1] = fmaf(hv.y, r1.y, acc[r][1]);
            acc[r][2] = fmaf(hv.y, r1.z, acc[r][2]);
            acc[r][3] = fmaf(hv.y, r1.w, acc[r][3]);
            acc[r][0] = fmaf(hv.z, r2.x, acc[r][0]);
            acc[r][1] = fmaf(hv.z, r2.y, acc[r][1]);
            acc[r][2] = fmaf(hv.z, r2.z, acc[r][2]);
            acc[r][3] = fmaf(hv.z, r2.w, acc[r][3]);
            acc[r][0] = fmaf(hv.w, r3.x, acc[r][0]);
            acc[r][1] = fmaf(hv.w, r3.y, acc[r][1]);
            acc[r][2] = fmaf(hv.w, r3.z, acc[r][2]);
            acc[r][3] = fmaf(hv.w, r3.w, acc[r][3]);
        }
    }

#pragma unroll
    for (int r = 0; r < 4; ++r) {
        int row = rowBase + rg * 4 + r;
        if (row < NN) {
            int lrow = rg * 4 + r;
            int c4s = cg ^ ((lrow >> 2) & 3);
            float4 ho = *(const float4*)(hs + lrow * 64 + c4s * 4);
            float4 o;
            float c0 = acc[r][0], c1 = acc[r][1], c2 = acc[r][2], c3 = acc[r][3];
            o.x = ho.x + (c0 > 0.f ? c0 : 0.f);
            o.y = ho.y + (c1 > 0.f ? c1 : 0.f);
            o.z = ho.z + (c2 > 0.f ? c2 : 0.f);
            o.w = ho.w + (c3 > 0.f ? c3 : 0.f);
            *(float4*)(h + (size_t)row * HD + cg * 4) = o;
            u16x4 ob;
            ob.x = f2bf(o.x); ob.y = f2bf(o.y); ob.z = f2bf(o.z); ob.w = f2bf(o.w);
            *(u16x4*)(hb + (size_t)row * HD + cg * 4) = ob;
        }
    }
}

// ---------------- Output GEMM: out = h @ Wout + b_out  [100000,64]x[64,256] ----------------

__global__ __launch_bounds__(256) void gemm_out_k(const float* __restrict__ h, const float* __restrict__ Wout,
                                                  const float* __restrict__ b_out, float* __restrict__ out) {
    __shared__ float hs[32 * 64];  // 8 KB
    int tid = threadIdx.x;
    int cg = tid & 63;       // cols 4*cg..4*cg+3 (0..255)
    int rg = tid >> 6;       // rows 8*rg..8*rg+7 (wave-uniform)
    int rowBase = blockIdx.x * 32;
#pragma unroll
    for (int i = 0; i < 2; ++i) {
        int idx = tid + 256 * i;  // 0..511
        int r = idx >> 4;
        int c4 = idx & 15;
        int grow = rowBase + r;
        if (grow >= NN) grow = NN - 1;
        *(float4*)(hs + r * 64 + c4 * 4) = *(const float4*)(h + (size_t)grow * HD + c4 * 4);
    }
    __syncthreads();

    float4 bb = *(const float4*)(b_out + cg * 4);
    float acc[8][4];
#pragma unroll
    for (int r = 0; r < 8; ++r) {
        acc[r][0] = bb.x; acc[r][1] = bb.y; acc[r][2] = bb.z; acc[r][3] = bb.w;
    }

#pragma unroll 2
    for (int k = 0; k < 64; k += 4) {
        float4 w0 = *(const float4*)(Wout + (size_t)(k + 0) * NC + cg * 4);
        float4 w1 = *(const float4*)(Wout + (size_t)(k + 1) * NC + cg * 4);
        float4 w2 = *(const float4*)(Wout + (size_t)(k + 2) * NC + cg * 4);
        float4 w3 = *(const float4*)(Wout + (size_t)(k + 3) * NC + cg * 4);
#pragma unroll
        for (int r = 0; r < 8; ++r) {
            float4 hv = *(const float4*)(hs + (rg * 8 + r) * 64 + k);
            acc[r][0] = fmaf(hv.x, w0.x, acc[r][0]);
            acc[r][1] = fmaf(hv.x, w0.y, acc[r][1]);
            acc[r][2] = fmaf(hv.x, w0.z, acc[r][2]);
            acc[r][3] = fmaf(hv.x, w0.w, acc[r][3]);
            acc[r][0] = fmaf(hv.y, w1.x, acc[r][0]);
            acc[r][1] = fmaf(hv.y, w1.y, acc[r][1]);
            acc[r][2] = fmaf(hv.y, w1.z, acc[r][2]);
            acc[r][3] = fmaf(hv.y, w1.w, acc[r][3]);
            acc[r][0] = fmaf(hv.z, w2.x, acc[r][0]);
            acc[r][1] = fmaf(hv.z, w2.y, acc[r][1]);
            acc[r][2] = fmaf(hv.z, w2.z, acc[r][2]);
            acc[r][3] = fmaf(hv.z, w2.w, acc[r][3]);
            acc[r][0] = fmaf(hv.w, w3.x, acc[r][0]);
            acc[r][1] = fmaf(hv.w, w3.y, acc[r][1]);
            acc[r][2] = fmaf(hv.w, w3.z, acc[r][2]);
            acc[r][3] = fmaf(hv.w, w3.w, acc[r][3]);
        }
    }
#pragma unroll
    for (int r = 0; r < 8; ++r) {
        int row = rowBase + rg * 8 + r;
        if (row < NN) {
            float4 o;
            o.x = acc[r][0]; o.y = acc[r][1]; o.z = acc[r][2]; o.w = acc[r][3];
            *(float4*)(out + (size_t)row * NC + cg * 4) = o;
        }
    }
}

extern "C" void kernel_launch(void* const* d_in, const int* in_sizes, int n_in,
                              void* d_out, int out_size, void* d_ws, size_t ws_size,
                              hipStream_t stream) {
    const float* x    = (const float*)d_in[0];
    const int*   ei   = (const int*)d_in[1];   // [2, E]: src then dst
    const float* Win  = (const float*)d_in[2];
    const float* b_in = (const float*)d_in[3];
    const float* Wl   = (const float*)d_in[4]; // [4,64,64]
    const float* bl   = (const float*)d_in[5]; // [4,64]
    const float* Wr   = (const float*)d_in[6]; // [4,64,64]
    const float* Wout = (const float*)d_in[7];
    const float* b_out= (const float*)d_in[8];
    float* out = (float*)d_out;

    const int* src = ei;
    const int* dst = ei + EE;

    // workspace layout (16B-aligned chunks)
    char* ws = (char*)d_ws;
    float* h        = (float*)ws;                         // 6.4M floats
    float* agg      = h + (size_t)NN * HD;                // 6.4M floats
    int*   rowptr   = (int*)(agg + (size_t)NN * HD);      // 100001 (pad to 100004)
    int*   csr      = rowptr + 100004;                    // 3.2M
    float* inv      = (float*)(csr + EE);                 // 100000
    int*   bucketptr= (int*)(inv + NN);                   // 392 (pad 400)
    unsigned short* wpk = (unsigned short*)(bucketptr + 400);  // 32768 (64 KB)
    unsigned short* hbf = wpk + 32768;                    // 6.4M bf16 (12.8 MB)

    // CSR-build scratch overlays on agg (dead until first aggregate):
    unsigned int* ebuf = (unsigned int*)agg;              // EE u32 (12.8 MB)
    int* hist  = (int*)agg + EE;                          // NEB*NB (611 KB)
    int* bboff = hist + NEB * NB;                         // NEB*NB (611 KB)

    pack_w<<<16, 256, 0, stream>>>(Win, wpk);

    part_count<<<NEB, 256, 0, stream>>>(dst, hist);
    bucket_ptr<<<1, 512, 0, stream>>>(hist, bucketptr);
    part_scan<<<NB, 512, 0, stream>>>(hist, bucketptr, bboff);
    part_scatter<<<NEB, 256, 0, stream>>>(src, dst, bboff, ebuf);
    bucket_fill2<<<NB, 256, 0, stream>>>(ebuf, bucketptr, rowptr, inv, csr);

    gemm_in<<<(NN + 127) / 128, 256, 0, stream>>>(x, wpk, b_in, h, hbf);

    for (int i = 0; i < 4; ++i) {
        aggregate<<<NN / 4, 256, 0, stream>>>(hbf, rowptr, csr, inv, (float4*)agg);
        layer_conv<<<(NN + 63) / 64, 256, 0, stream>>>(agg, h, hbf, Wl + (size_t)i * HD * HD,
                                                       Wr + (size_t)i * HD * HD, bl + (size_t)i * HD);
    }

    gemm_out_k<<<(NN + 31) / 32, 256, 0, stream>>>(h, Wout, b_out, out);
}

// Round 6
// 901.263 us; speedup vs baseline: 1.6651x; 1.1136x over previous
//
#include <hip/hip_runtime.h>
#include <hip/hip_bf16.h>

#define NN 100000
#define EE 3200000
#define HD 64
#define NF 512
#define NC 256

// ---- bucketed CSR-build parameters ----
#define BSH 8                 // 256 nodes per bucket
#define NB 391                // ceil(NN/256)
#define EB 8192               // edges per partition block
#define NEB 391               // ceil(EE/EB)

typedef __attribute__((ext_vector_type(8))) short bf16x8;
typedef __attribute__((ext_vector_type(4))) float f32x4;
typedef __attribute__((ext_vector_type(4))) unsigned short u16x4;

__device__ __forceinline__ unsigned short f2bf(float f) {
    unsigned u = __float_as_uint(f);
    return (unsigned short)((u + 0x7FFFu + ((u >> 16) & 1u)) >> 16);  // RNE
}
__device__ __forceinline__ unsigned pack2(float a, float b) {
    return (unsigned)f2bf(a) | ((unsigned)f2bf(b) << 16);
}
__device__ __forceinline__ float bf2f(unsigned short v) {
    return __uint_as_float(((unsigned)v) << 16);
}

// ---------------- bucketed edge partition ----------------

__global__ __launch_bounds__(256) void part_count(const int* __restrict__ dst, int* __restrict__ hist) {
    __shared__ int hs[NB];
    int t = threadIdx.x, blk = blockIdx.x;
    for (int b = t; b < NB; b += 256) hs[b] = 0;
    __syncthreads();
    int base = blk * EB;
#pragma unroll
    for (int i = 0; i < EB / 256; ++i) {
        int e = base + t + 256 * i;
        if (e < EE) atomicAdd(&hs[dst[e] >> BSH], 1);
    }
    __syncthreads();
    for (int b = t; b < NB; b += 256) hist[blk * NB + b] = hs[b];
}

__global__ __launch_bounds__(512) void bucket_ptr(const int* __restrict__ hist, int* __restrict__ bucketptr) {
    __shared__ int s[512];
    int t = threadIdx.x;
    int v = 0;
    if (t < NB) {
        for (int blk = 0; blk < NEB; ++blk) v += hist[blk * NB + t];
    }
    s[t] = v; __syncthreads();
    for (int d = 1; d < 512; d <<= 1) {
        int a = (t >= d) ? s[t - d] : 0;
        __syncthreads();
        s[t] += a;
        __syncthreads();
    }
    if (t < NB) bucketptr[t] = s[t] - v;  // exclusive
    if (t == 0) bucketptr[NB] = EE;
}

__global__ __launch_bounds__(512) void part_scan(const int* __restrict__ hist, const int* __restrict__ bucketptr,
                                                 int* __restrict__ bboff) {
    __shared__ int s[512];
    int b = blockIdx.x, t = threadIdx.x;
    int v = (t < NEB) ? hist[t * NB + b] : 0;
    s[t] = v; __syncthreads();
    for (int d = 1; d < 512; d <<= 1) {
        int a = (t >= d) ? s[t - d] : 0;
        __syncthreads();
        s[t] += a;
        __syncthreads();
    }
    if (t < NEB) bboff[t * NB + b] = bucketptr[b] + s[t] - v;  // exclusive
}

__global__ __launch_bounds__(256) void part_scatter(const int* __restrict__ src, const int* __restrict__ dst,
                                                    const int* __restrict__ bboff, unsigned int* __restrict__ ebuf) {
    __shared__ int off[NB];
    __shared__ int rank[NB];
    int t = threadIdx.x, blk = blockIdx.x;
    for (int b = t; b < NB; b += 256) { off[b] = bboff[blk * NB + b]; rank[b] = 0; }
    __syncthreads();
    int base = blk * EB;
#pragma unroll
    for (int i = 0; i < EB / 256; ++i) {
        int e = base + t + 256 * i;
        if (e < EE) {
            int d = dst[e];
            int s = src[e];
            int b = d >> BSH;
            int r = atomicAdd(&rank[b], 1);
            ebuf[off[b] + r] = (unsigned)s | ((unsigned)(d & 255) << 17);
        }
    }
}

__global__ __launch_bounds__(256) void bucket_fill2(const unsigned int* __restrict__ ebuf,
                                                    const int* __restrict__ bucketptr,
                                                    int* __restrict__ rowptr, float* __restrict__ inv,
                                                    int* __restrict__ csr) {
    __shared__ int hcnt[256];
    __shared__ int scn[256];
    __shared__ int cur[256];
    int t = threadIdx.x, b = blockIdx.x;
    int n0 = b << BSH;
    hcnt[t] = 0;
    __syncthreads();
    int estart = bucketptr[b];
    int eend = bucketptr[b + 1];
    for (int e = estart + t; e < eend; e += 256) {
        atomicAdd(&hcnt[ebuf[e] >> 17], 1);
    }
    __syncthreads();
    int v = hcnt[t];
    scn[t] = v;
    __syncthreads();
    for (int d = 1; d < 256; d <<= 1) {
        int a = (t >= d) ? scn[t - d] : 0;
        __syncthreads();
        scn[t] += a;
        __syncthreads();
    }
    int off = estart + scn[t] - v;  // exclusive within bucket
    cur[t] = off;
    if (n0 + t < NN) {
        rowptr[n0 + t] = off;
        inv[n0 + t] = 1.0f / (float)(v > 1 ? v : 1);
    }
    if (b == NB - 1 && t == 0) rowptr[NN] = EE;
    __syncthreads();
    for (int e = estart + t; e < eend; e += 256) {
        unsigned u = ebuf[e];
        int dL = (int)(u >> 17);
        int p = atomicAdd(&cur[dL], 1);
        csr[p] = (int)(u & 0x1FFFFu);
    }
}

// ---------------- weight packing (bf16 MFMA fragment order) ----------------
// frag convention (proven in gemm_in r3): frag[t][c][lane][j] = W[t*32 + (lane>>4)*8 + j][c*16 + (lane&15)]

__global__ __launch_bounds__(256) void pack_w(const float* __restrict__ Win, unsigned short* __restrict__ wpk) {
    int id = blockIdx.x * 256 + threadIdx.x;  // 0..4095: t(16) x c(4) x lane(64)
    int l = id & 63;
    int c = (id >> 6) & 3;
    int t = id >> 8;
    int kbase = t * 32 + (l >> 4) * 8;
    int col = c * 16 + (l & 15);
    float f[8];
#pragma unroll
    for (int j = 0; j < 8; ++j) f[j] = Win[(size_t)(kbase + j) * HD + col];
    uint4 p;
    p.x = pack2(f[0], f[1]); p.y = pack2(f[2], f[3]);
    p.z = pack2(f[4], f[5]); p.w = pack2(f[6], f[7]);
    *(uint4*)(wpk + (size_t)id * 8) = p;
}

// Wcat = [Wl_i ; Wr_i] (128x64) per layer, K=128 -> t=0..3.
__global__ __launch_bounds__(256) void pack_wl(const float* __restrict__ Wl, const float* __restrict__ Wr,
                                               unsigned short* __restrict__ wlpk) {
    int id = blockIdx.x * 256 + threadIdx.x;  // 0..4095: layer(4) x t(4) x c(4) x lane(64)
    int l = id & 63;
    int c = (id >> 6) & 3;
    int t = (id >> 8) & 3;
    int i = id >> 10;
    int kbase = t * 32 + (l >> 4) * 8;
    int col = c * 16 + (l & 15);
    float f[8];
#pragma unroll
    for (int j = 0; j < 8; ++j) {
        int k = kbase + j;
        f[j] = (k < 64) ? Wl[(size_t)i * 4096 + (size_t)k * HD + col]
                        : Wr[(size_t)i * 4096 + (size_t)(k - 64) * HD + col];
    }
    uint4 p;
    p.x = pack2(f[0], f[1]); p.y = pack2(f[2], f[3]);
    p.z = pack2(f[4], f[5]); p.w = pack2(f[6], f[7]);
    *(uint4*)(wlpk + (size_t)id * 8) = p;
}

// Wout 64x256, K=64 -> t=0..1, c=0..15.
__global__ __launch_bounds__(256) void pack_wout(const float* __restrict__ Wout, unsigned short* __restrict__ wopk) {
    int id = blockIdx.x * 256 + threadIdx.x;  // 0..2047: t(2) x c(16) x lane(64)
    int l = id & 63;
    int c = (id >> 6) & 15;
    int t = id >> 10;
    int kbase = t * 32 + (l >> 4) * 8;
    int col = c * 16 + (l & 15);
    float f[8];
#pragma unroll
    for (int j = 0; j < 8; ++j) f[j] = Wout[(size_t)(kbase + j) * NC + col];
    uint4 p;
    p.x = pack2(f[0], f[1]); p.y = pack2(f[2], f[3]);
    p.z = pack2(f[4], f[5]); p.w = pack2(f[6], f[7]);
    *(uint4*)(wopk + (size_t)id * 8) = p;
}

// ---------------- GEMM: h = x @ Win + b_in via bf16 MFMA (writes h fp32 + hb bf16) ----------------

__global__ __launch_bounds__(256) void gemm_in(const float* __restrict__ x, const unsigned short* __restrict__ wpk,
                                               const float* __restrict__ b_in, float* __restrict__ h,
                                               unsigned short* __restrict__ hb) {
    __shared__ unsigned short xs[128 * 64];  // 16 KB bf16
    int tid = threadIdx.x;
    int lane = tid & 63;
    int w = tid >> 6;
    int rowBase = blockIdx.x * 128;
    int lr = lane & 15;
    int lg = lane >> 4;

    f32x4 acc[2][4];
#pragma unroll
    for (int c = 0; c < 4; ++c) {
        float bb = b_in[c * 16 + lr];
#pragma unroll
        for (int m = 0; m < 2; ++m) acc[m][c] = (f32x4){bb, bb, bb, bb};
    }

    for (int kt = 0; kt < NF; kt += 64) {  // 8 tiles
        __syncthreads();
#pragma unroll
        for (int i = 0; i < 4; ++i) {
            int idx = tid + 256 * i;   // 0..1023
            int r = idx >> 3;          // tile row 0..127
            int u = idx & 7;           // 16B unit (8 bf16) within row
            int grow = rowBase + r;
            if (grow >= NN) grow = NN - 1;
            const float* srcp = x + (size_t)grow * NF + kt + u * 8;
            float4 a = *(const float4*)(srcp);
            float4 b = *(const float4*)(srcp + 4);
            uint4 p;
            p.x = pack2(a.x, a.y); p.y = pack2(a.z, a.w);
            p.z = pack2(b.x, b.y); p.w = pack2(b.z, b.w);
            int u2 = u ^ (r & 7);
            *(uint4*)(xs + (size_t)r * 64 + u2 * 8) = p;
        }
        __syncthreads();
#pragma unroll
        for (int ks = 0; ks < 2; ++ks) {
            int tstep = (kt >> 5) + ks;
            bf16x8 av[2], bv[4];
#pragma unroll
            for (int m = 0; m < 2; ++m) {
                int r = w * 32 + m * 16 + lr;
                int u2 = (ks * 4 + lg) ^ (r & 7);
                av[m] = *(const bf16x8*)(xs + (size_t)r * 64 + u2 * 8);
            }
#pragma unroll
            for (int c = 0; c < 4; ++c) {
                bv[c] = *(const bf16x8*)(wpk + (((size_t)tstep * 4 + c) * 64 + lane) * 8);
            }
#pragma unroll
            for (int m = 0; m < 2; ++m)
#pragma unroll
                for (int c = 0; c < 4; ++c)
                    acc[m][c] = __builtin_amdgcn_mfma_f32_16x16x32_bf16(av[m], bv[c], acc[m][c], 0, 0, 0);
        }
    }

#pragma unroll
    for (int m = 0; m < 2; ++m) {
        int rbase = rowBase + w * 32 + m * 16 + lg * 4;
#pragma unroll
        for (int j = 0; j < 4; ++j) {
            int row = rbase + j;
            if (row < NN) {
#pragma unroll
                for (int c = 0; c < 4; ++c) {
                    float v = acc[m][c][j];
                    h[(size_t)row * HD + c * 16 + lr] = v;
                    hb[(size_t)row * HD + c * 16 + lr] = f2bf(v);
                }
            }
        }
    }
}

// ---------------- Fused layer: gather-mean + conv + relu + residual ----------------
// 16 waves/block, wave w gathers node blockIdx*16+w (8-edge unrolled loop on hbin),
// agg row -> LDS bf16 (XOR-swizzled 16B units); h row staged fp32 (residual) + bf16.
// Phase B: waves 0..3 compute 16x64 conv = [agg|h] @ [Wl;Wr] (K=128) as 4 MFMA chains.
// Reads OLD buffers (hin/hbin), writes NEW (hout/hbout) -- ping-pong kills the
// same-launch gather/update race. 100000 = 16*6250 exactly, no tail.

__global__ __launch_bounds__(1024) void layer_fused(const float* __restrict__ hin,
                                                    const unsigned short* __restrict__ hbin,
                                                    const int* __restrict__ rowptr, const int* __restrict__ csr,
                                                    const float* __restrict__ inv,
                                                    const unsigned short* __restrict__ wlpk,
                                                    const float* __restrict__ bl,
                                                    float* __restrict__ hout, unsigned short* __restrict__ hbout) {
    __shared__ unsigned short a_bf[16 * 64];  // 2 KB: agg rows, swizzled units
    __shared__ unsigned short h_bf[16 * 64];  // 2 KB: h rows bf16, swizzled units
    __shared__ float h_f[16 * 64];            // 4 KB: h rows fp32 (residual)
    int tid = threadIdx.x;
    int w = tid >> 6;          // node slot 0..15
    int lane = tid & 63;
    int node = __builtin_amdgcn_readfirstlane(blockIdx.x * 16 + w);

    // ---- phase A: gather-mean for this wave's node ----
    int q = lane >> 4;
    int f = lane & 15;
    int start = rowptr[node];
    int end = rowptr[node + 1];

    float4 acc0 = make_float4(0.f, 0.f, 0.f, 0.f);
    float4 acc1 = make_float4(0.f, 0.f, 0.f, 0.f);
    int e = start;
    int end8 = start + ((end - start) & ~7);
    for (; e < end8; e += 8) {
        int s0 = csr[e + q];
        int s1 = csr[e + 4 + q];
        u16x4 v0 = *(const u16x4*)(hbin + (size_t)s0 * HD + f * 4);
        u16x4 v1 = *(const u16x4*)(hbin + (size_t)s1 * HD + f * 4);
        acc0.x += bf2f(v0.x); acc0.y += bf2f(v0.y); acc0.z += bf2f(v0.z); acc0.w += bf2f(v0.w);
        acc1.x += bf2f(v1.x); acc1.y += bf2f(v1.y); acc1.z += bf2f(v1.z); acc1.w += bf2f(v1.w);
    }
    if (e + q < end) {
        int s = csr[e + q];
        u16x4 v = *(const u16x4*)(hbin + (size_t)s * HD + f * 4);
        acc0.x += bf2f(v.x); acc0.y += bf2f(v.y); acc0.z += bf2f(v.z); acc0.w += bf2f(v.w);
    }
    e += 4;
    if (e + q < end) {
        int s = csr[e + q];
        u16x4 v = *(const u16x4*)(hbin + (size_t)s * HD + f * 4);
        acc1.x += bf2f(v.x); acc1.y += bf2f(v.y); acc1.z += bf2f(v.z); acc1.w += bf2f(v.w);
    }
    float4 a;
    a.x = acc0.x + acc1.x;
    a.y = acc0.y + acc1.y;
    a.z = acc0.z + acc1.z;
    a.w = acc0.w + acc1.w;
    a.x += __shfl_xor(a.x, 16); a.x += __shfl_xor(a.x, 32);
    a.y += __shfl_xor(a.y, 16); a.y += __shfl_xor(a.y, 32);
    a.z += __shfl_xor(a.z, 16); a.z += __shfl_xor(a.z, 32);
    a.w += __shfl_xor(a.w, 16); a.w += __shfl_xor(a.w, 32);
    if (q == 0) {
        float s = inv[node];
        int u = f >> 1;
        int u2 = u ^ (w & 7);
        u16x4 ob;
        ob.x = f2bf(a.x * s); ob.y = f2bf(a.y * s); ob.z = f2bf(a.z * s); ob.w = f2bf(a.w * s);
        *(u16x4*)(a_bf + w * 64 + u2 * 8 + (f & 1) * 4) = ob;
    }
    // stage h row: fp32 for residual, bf16 (swizzled) for MFMA A
    {
        float hv = hin[(size_t)node * HD + lane];
        h_f[w * 64 + lane] = hv;
        int u = lane >> 3;
        int u2 = u ^ (w & 7);
        h_bf[w * 64 + u2 * 8 + (lane & 7)] = f2bf(hv);
    }
    __syncthreads();

    // ---- phase B: waves 0..3, col-frag c = w ----
    if (w < 4) {
        int c = w;
        int lr = lane & 15;
        int lg = lane >> 4;
        float bb = bl[c * 16 + lr];
        f32x4 acc = (f32x4){bb, bb, bb, bb};
#pragma unroll
        for (int t = 0; t < 4; ++t) {
            const unsigned short* asrc = (t < 2) ? a_bf : h_bf;
            int ks = t & 1;
            int u2 = (ks * 4 + lg) ^ (lr & 7);
            bf16x8 av = *(const bf16x8*)(asrc + (size_t)lr * 64 + u2 * 8);
            bf16x8 bv = *(const bf16x8*)(wlpk + (((size_t)t * 4 + c) * 64 + lane) * 8);
            acc = __builtin_amdgcn_mfma_f32_16x16x32_bf16(av, bv, acc, 0, 0, 0);
        }
#pragma unroll
        for (int j = 0; j < 4; ++j) {
            int nl = lg * 4 + j;
            int gnode = blockIdx.x * 16 + nl;
            float ho = h_f[nl * 64 + c * 16 + lr];
            float cv = acc[j];
            float o = ho + (cv > 0.f ? cv : 0.f);
            hout[(size_t)gnode * HD + c * 16 + lr] = o;
            hbout[(size_t)gnode * HD + c * 16 + lr] = f2bf(o);
        }
    }
}

// ---------------- Output GEMM: out = h @ Wout + b_out via bf16 MFMA ----------------
// 4 waves x 16 rows; A-frags straight from hb (2x16B/lane), 16 col-frags x 2 K-steps.

__global__ __launch_bounds__(256) void gemm_out_m(const unsigned short* __restrict__ hb,
                                                  const unsigned short* __restrict__ wopk,
                                                  const float* __restrict__ b_out, float* __restrict__ out) {
    int tid = threadIdx.x;
    int lane = tid & 63;
    int w = tid >> 6;
    int rowBase = blockIdx.x * 64 + w * 16;
    int lr = lane & 15;
    int lg = lane >> 4;

    int row = rowBase + lr;
    int rrow = (row < NN) ? row : NN - 1;
    bf16x8 av0 = *(const bf16x8*)(hb + (size_t)rrow * HD + lg * 8);
    bf16x8 av1 = *(const bf16x8*)(hb + (size_t)rrow * HD + 32 + lg * 8);

    f32x4 acc[16];
#pragma unroll
    for (int c = 0; c < 16; ++c) {
        float bb = b_out[c * 16 + lr];
        acc[c] = (f32x4){bb, bb, bb, bb};
        bf16x8 b0 = *(const bf16x8*)(wopk + (((size_t)0 * 16 + c) * 64 + lane) * 8);
        bf16x8 b1 = *(const bf16x8*)(wopk + (((size_t)1 * 16 + c) * 64 + lane) * 8);
        acc[c] = __builtin_amdgcn_mfma_f32_16x16x32_bf16(av0, b0, acc[c], 0, 0, 0);
        acc[c] = __builtin_amdgcn_mfma_f32_16x16x32_bf16(av1, b1, acc[c], 0, 0, 0);
    }
#pragma unroll
    for (int c = 0; c < 16; ++c) {
#pragma unroll
        for (int j = 0; j < 4; ++j) {
            int r = rowBase + lg * 4 + j;
            if (r < NN) out[(size_t)r * NC + c * 16 + lr] = acc[c][j];
        }
    }
}

extern "C" void kernel_launch(void* const* d_in, const int* in_sizes, int n_in,
                              void* d_out, int out_size, void* d_ws, size_t ws_size,
                              hipStream_t stream) {
    const float* x    = (const float*)d_in[0];
    const int*   ei   = (const int*)d_in[1];   // [2, E]: src then dst
    const float* Win  = (const float*)d_in[2];
    const float* b_in = (const float*)d_in[3];
    const float* Wl   = (const float*)d_in[4]; // [4,64,64]
    const float* bl   = (const float*)d_in[5]; // [4,64]
    const float* Wr   = (const float*)d_in[6]; // [4,64,64]
    const float* Wout = (const float*)d_in[7];
    const float* b_out= (const float*)d_in[8];
    float* out = (float*)d_out;

    const int* src = ei;
    const int* dst = ei + EE;

    // workspace layout (16B-aligned chunks)
    char* ws = (char*)d_ws;
    float* h0       = (float*)ws;                         // 6.4M floats
    float* h1       = h0 + (size_t)NN * HD;               // 6.4M floats (ping-pong)
    int*   rowptr   = (int*)(h1 + (size_t)NN * HD);       // 100001 (pad 100004)
    int*   csr      = rowptr + 100004;                    // 3.2M
    float* inv      = (float*)(csr + EE);                 // 100000
    int*   bucketptr= (int*)(inv + NN);                   // 392 (pad 400)
    unsigned short* wpk  = (unsigned short*)(bucketptr + 400);  // 32768 u16
    unsigned short* wlpk = wpk + 32768;                   // 32768 u16 (4 layers)
    unsigned short* wopk = wlpk + 32768;                  // 16384 u16
    unsigned short* hb0  = wopk + 16384;                  // 6.4M u16
    unsigned short* hb1  = hb0 + (size_t)NN * HD;         // 6.4M u16

    // CSR-build scratch overlays on h1 (dead until layer 0 writes it):
    unsigned int* ebuf = (unsigned int*)h1;               // EE u32 (12.8 MB)
    int* hist  = (int*)h1 + EE;                           // NEB*NB
    int* bboff = hist + NEB * NB;                         // NEB*NB

    pack_w<<<16, 256, 0, stream>>>(Win, wpk);
    pack_wl<<<16, 256, 0, stream>>>(Wl, Wr, wlpk);
    pack_wout<<<8, 256, 0, stream>>>(Wout, wopk);

    part_count<<<NEB, 256, 0, stream>>>(dst, hist);
    bucket_ptr<<<1, 512, 0, stream>>>(hist, bucketptr);
    part_scan<<<NB, 512, 0, stream>>>(hist, bucketptr, bboff);
    part_scatter<<<NEB, 256, 0, stream>>>(src, dst, bboff, ebuf);
    bucket_fill2<<<NB, 256, 0, stream>>>(ebuf, bucketptr, rowptr, inv, csr);

    gemm_in<<<(NN + 127) / 128, 256, 0, stream>>>(x, wpk, b_in, h0, hb0);

    float* hA = h0; unsigned short* hbA = hb0;
    float* hB = h1; unsigned short* hbB = hb1;
    for (int i = 0; i < 4; ++i) {
        layer_fused<<<NN / 16, 1024, 0, stream>>>(hA, hbA, rowptr, csr, inv,
                                                  wlpk + (size_t)i * 8192, bl + (size_t)i * HD, hB, hbB);
        float* tf = hA; hA = hB; hB = tf;
        unsigned short* tb = hbA; hbA = hbB; hbB = tb;
    }
    // after 4 swaps final h is back in h0/hb0 (= hA)

    gemm_out_m<<<(NN + 63) / 64, 256, 0, stream>>>(hbA, wopk, b_out, out);
}